// Round 1
// baseline (2245.012 us; speedup 1.0000x reference)
//
#include <hip/hip_runtime.h>

// Problem constants (fixed by the reference)
#define N_PTS   16384        // 16*32*32 flattened points
#define DIM     512
#define K_CODES 8192
#define SPLIT   4            // K split across blockIdx.y
#define KS      (K_CODES / SPLIT)   // 2048 codes per split
#define MT      128          // points per block tile
#define KT      128          // codes per block tile
#define DT      32           // dims per LDS chunk
#define PITCH   36           // LDS row pitch (floats): 36 mod 32 = 4 -> conflict-free compute reads
#define OUT0_N  (N_PTS * DIM)          // 8388608
#define NELEM_F (8388608.0f)

// ---------------------------------------------------------------- kernel 1
// |c_k|^2 for each codebook row (block per row, 128 threads * float4 = 512)
__global__ __launch_bounds__(128) void cnorm_kernel(const float* __restrict__ cb,
                                                    float* __restrict__ cnorm) {
    const int k = blockIdx.x;
    const int t = threadIdx.x;
    const float4 v = *(const float4*)(cb + (size_t)k * DIM + t * 4);
    float s = v.x * v.x + v.y * v.y + v.z * v.z + v.w * v.w;
#pragma unroll
    for (int o = 32; o > 0; o >>= 1) s += __shfl_down(s, o, 64);
    __shared__ float red[2];
    if ((t & 63) == 0) red[t >> 6] = s;
    __syncthreads();
    if (t == 0) cnorm[k] = red[0] + red[1];
}

// ---------------------------------------------------------------- kernel 2
// Tiled distance + argmin. Block tile: MT=128 points x KT=128 codes.
// 256 threads as 16x16; each thread owns an 8x8 register tile.
// Score s = |c|^2 - 2 x.c  (|x|^2 dropped: constant per point, avoids
// quantizing comparisons at ulp(512)).
__global__ __launch_bounds__(256, 2) void dist_argmin_kernel(
    const float* __restrict__ z_e, const float* __restrict__ cb,
    const float* __restrict__ cnorm,
    float* __restrict__ pmin, int* __restrict__ pidx) {
    __shared__ float xs[MT * PITCH];   // 128 x 36 floats (18432 B)
    __shared__ float cs[KT * PITCH];

    const int tid = threadIdx.x;
    const int tx = tid & 15;           // code sub-index
    const int ty = tid >> 4;           // point sub-index
    const int pbase = blockIdx.x * MT;
    const int kbase0 = blockIdx.y * KS;

    // staging coordinates: 128 rows x 8 float4 (DT=32 dims) per buffer
    const int scol = (tid & 7) * 4;    // dim offset (float4)
    const int srow0 = tid >> 3;        // 0..31, step 32 per iteration

    float mn[8], acc[8][8];
    int mi[8];
#pragma unroll
    for (int i = 0; i < 8; ++i) { mn[i] = 3.0e38f; mi[i] = 0; }

    for (int kt = 0; kt < KS / KT; ++kt) {          // 16 code tiles
        const int kbase = kbase0 + kt * KT;
#pragma unroll
        for (int i = 0; i < 8; ++i)
#pragma unroll
            for (int j = 0; j < 8; ++j) acc[i][j] = 0.0f;

        for (int dc = 0; dc < DIM / DT; ++dc) {     // 16 dim chunks
            const int dbase = dc * DT;
            __syncthreads();
#pragma unroll
            for (int it = 0; it < 4; ++it) {
                const int row = srow0 + it * 32;
                *(float4*)(xs + row * PITCH + scol) =
                    *(const float4*)(z_e + (size_t)(pbase + row) * DIM + dbase + scol);
                *(float4*)(cs + row * PITCH + scol) =
                    *(const float4*)(cb + (size_t)(kbase + row) * DIM + dbase + scol);
            }
            __syncthreads();
#pragma unroll 2
            for (int dd = 0; dd < DT; dd += 4) {
                float4 xv[8], cv[8];
#pragma unroll
                for (int i = 0; i < 8; ++i)
                    xv[i] = *(const float4*)(xs + (ty + 16 * i) * PITCH + dd);
#pragma unroll
                for (int j = 0; j < 8; ++j)
                    cv[j] = *(const float4*)(cs + (tx + 16 * j) * PITCH + dd);
#pragma unroll
                for (int i = 0; i < 8; ++i)
#pragma unroll
                    for (int j = 0; j < 8; ++j)
                        acc[i][j] += xv[i].x * cv[j].x + xv[i].y * cv[j].y +
                                     xv[i].z * cv[j].z + xv[i].w * cv[j].w;
            }
        }
        // fold this code tile into the running per-point argmin
#pragma unroll
        for (int j = 0; j < 8; ++j) {
            const int k = kbase + tx + 16 * j;      // ascending k for fixed tx
            const float cn = cnorm[k];
#pragma unroll
            for (int i = 0; i < 8; ++i) {
                const float s = cn - 2.0f * acc[i][j];
                if (s < mn[i]) { mn[i] = s; mi[i] = k; }   // strict <: first index wins ties
            }
        }
    }

    // cross-thread (over tx) reduction per point; alias LDS (done with tiles)
    float* rmin = xs;        // [MT][16]
    int* ridx = (int*)cs;    // [MT][16]
    __syncthreads();
#pragma unroll
    for (int i = 0; i < 8; ++i) {
        const int p = ty + 16 * i;
        rmin[p * 16 + tx] = mn[i];
        ridx[p * 16 + tx] = mi[i];
    }
    __syncthreads();
    if (tid < MT) {
        float best = rmin[tid * 16];
        int bi = ridx[tid * 16];
#pragma unroll
        for (int t = 1; t < 16; ++t) {
            const float v = rmin[tid * 16 + t];
            const int k2 = ridx[tid * 16 + t];
            if (v < best || (v == best && k2 < bi)) { best = v; bi = k2; }
        }
        pmin[(size_t)blockIdx.y * N_PTS + pbase + tid] = best;
        pidx[(size_t)blockIdx.y * N_PTS + pbase + tid] = bi;
    }
}

// ---------------------------------------------------------------- kernel 3
// Per-point: merge split partials -> final index; gather code row; write
// z_q_st = z_e + (z_q - z_e) (exact reference op order); partial loss sum;
// histogram count; index as float.
__global__ __launch_bounds__(128) void gather_kernel(
    const float* __restrict__ z_e, const float* __restrict__ cb,
    const float* __restrict__ pmin, const int* __restrict__ pidx,
    float* __restrict__ out_q, float* __restrict__ out_idx,
    unsigned int* __restrict__ counts, float* __restrict__ psums) {
    const int p = blockIdx.x;
    const int t = threadIdx.x;
    float best = pmin[p];
    int bi = pidx[p];
#pragma unroll
    for (int s = 1; s < SPLIT; ++s) {
        const float v = pmin[(size_t)s * N_PTS + p];
        const int k2 = pidx[(size_t)s * N_PTS + p];
        if (v < best || (v == best && k2 < bi)) { best = v; bi = k2; }
    }
    const float4 z = *(const float4*)(z_e + (size_t)p * DIM + t * 4);
    const float4 c = *(const float4*)(cb + (size_t)bi * DIM + t * 4);
    float4 d, o;
    d.x = c.x - z.x; d.y = c.y - z.y; d.z = c.z - z.z; d.w = c.w - z.w;
    o.x = z.x + d.x; o.y = z.y + d.y; o.z = z.z + d.z; o.w = z.w + d.w;
    *(float4*)(out_q + (size_t)p * DIM + t * 4) = o;
    float ls = d.x * d.x + d.y * d.y + d.z * d.z + d.w * d.w;
#pragma unroll
    for (int off = 32; off > 0; off >>= 1) ls += __shfl_down(ls, off, 64);
    __shared__ float red[2];
    if ((t & 63) == 0) red[t >> 6] = ls;
    __syncthreads();
    if (t == 0) {
        psums[p] = red[0] + red[1];
        out_idx[p] = (float)bi;
        atomicAdd(&counts[bi], 1u);
    }
}

// ---------------------------------------------------------------- kernel 4
// losses + perplexity (single block)
__global__ __launch_bounds__(256) void finalize_kernel(
    const unsigned int* __restrict__ counts, const float* __restrict__ psums,
    float* __restrict__ out_scalars) {
    const int t = threadIdx.x;
    float ent = 0.0f;
    for (int b = t; b < K_CODES; b += 256) {
        const float pr = (float)counts[b] * (1.0f / 16384.0f);
        ent += pr * logf(pr + 1e-10f);      // pr==0 -> 0 * log(1e-10) = 0
    }
    float ss = 0.0f;
    for (int i = t; i < N_PTS; i += 256) ss += psums[i];
#pragma unroll
    for (int off = 32; off > 0; off >>= 1) {
        ent += __shfl_down(ent, off, 64);
        ss += __shfl_down(ss, off, 64);
    }
    __shared__ float re[4], rs[4];
    if ((t & 63) == 0) { re[t >> 6] = ent; rs[t >> 6] = ss; }
    __syncthreads();
    if (t == 0) {
        const float loss = (rs[0] + rs[1] + rs[2] + rs[3]) * (1.0f / NELEM_F);
        out_scalars[0] = loss;              // commitment_loss
        out_scalars[1] = loss;              // codebook_loss (same value)
        out_scalars[2] = expf(-(re[0] + re[1] + re[2] + re[3]));  // perplexity
    }
}

extern "C" void kernel_launch(void* const* d_in, const int* in_sizes, int n_in,
                              void* d_out, int out_size, void* d_ws, size_t ws_size,
                              hipStream_t stream) {
    const float* z_e = (const float*)d_in[0];
    const float* cb  = (const float*)d_in[1];
    float* out = (float*)d_out;
    char* ws = (char*)d_ws;

    // workspace layout (640 KB total)
    float* cnorm        = (float*)ws;                                  // 32 KB
    float* pmin         = (float*)(ws + 32768);                        // 256 KB
    int* pidx           = (int*)(ws + 32768 + 262144);                 // 256 KB
    unsigned int* counts= (unsigned int*)(ws + 32768 + 2 * 262144);    // 32 KB
    float* psums        = (float*)(ws + 32768 + 2 * 262144 + 32768);   // 64 KB

    hipMemsetAsync(counts, 0, 32768, stream);                // counts must start at 0
    cnorm_kernel<<<K_CODES, 128, 0, stream>>>(cb, cnorm);
    dim3 grid1(N_PTS / MT, SPLIT);                           // 128 x 4 = 512 blocks
    dist_argmin_kernel<<<grid1, 256, 0, stream>>>(z_e, cb, cnorm, pmin, pidx);
    gather_kernel<<<N_PTS, 128, 0, stream>>>(z_e, cb, pmin, pidx,
                                             out, out + OUT0_N, counts, psums);
    finalize_kernel<<<1, 256, 0, stream>>>(counts, psums, out + OUT0_N + N_PTS);
}

// Round 3
// 1593.530 us; speedup vs baseline: 1.4088x; 1.4088x over previous
//
#include <hip/hip_runtime.h>

// ---------------------------------------------------------------------------
// VectorQuantizer: N=16384 points x K=8192 codes x D=512 fp32.
// Fast path: fp16 split (hi+lo) GEMM on MFMA with augmented K'=1536
//   dot = hi.hi + hi.lo + lo.hi  (error ~2e-6, lo.lo ~2^-22 dropped)
// Fused top-2 argmin epilogue (with inter-wave LDS merge — round-2 race fix)
// + fp64 rescore of near-ties (margin 3e-3).
// Fallback (small ws): round-1 pure-fp32 VALU kernel (known-correct).
// ---------------------------------------------------------------------------

#define N_PTS   16384
#define DIM     512
#define K_CODES 8192
#define K3      1536                  // augmented K'
#define NSPLIT  16                    // code splits (512 codes each)
#define OUT0_N  (N_PTS * DIM)
#define NELEM_F (8388608.0f)
#define MARGIN  3.0e-3f

typedef _Float16 half8 __attribute__((ext_vector_type(8)));
typedef _Float16 f16x4 __attribute__((ext_vector_type(4)));
typedef float    f32x4 __attribute__((ext_vector_type(4)));

struct RescEntry { int p; int n; int cand[6]; };

// fast-path workspace layout (bytes)
#define SZ_A3    (16384UL * 1536 * 2)              // 50331648
#define SZ_B3    (8192UL * 1536 * 2)               // 25165824
#define OFF_A3   0UL
#define OFF_B3   (OFF_A3 + SZ_A3)
#define OFF_CN   (OFF_B3 + SZ_B3)                  // cnorm 32 KB
#define OFF_PV1  (OFF_CN + 32768UL)
#define SZ_P     (16UL * 16384 * 4)                // 1 MB each
#define OFF_PI1  (OFF_PV1 + SZ_P)
#define OFF_PV2  (OFF_PI1 + SZ_P)
#define OFF_PI2  (OFF_PV2 + SZ_P)
#define OFF_FIN  (OFF_PI2 + SZ_P)                  // final_idx 64 KB
#define OFF_PSUM (OFF_FIN + 65536UL)               // psums 64 KB
#define OFF_CNT  (OFF_PSUM + 65536UL)              // counts 32 KB
#define OFF_RCNT (OFF_CNT + 32768UL)               // resc_count (pad 256)
#define OFF_RLST (OFF_RCNT + 256UL)                // 4096 * 32 B
#define WS_NEED  (OFF_RLST + 4096UL * 32UL)

#define GLOAD_LDS16(g, l) \
    __builtin_amdgcn_global_load_lds( \
        (const __attribute__((address_space(1))) unsigned int*)(g), \
        (__attribute__((address_space(3))) unsigned int*)(l), 16, 0, 0)

// ---------------------------------------------------------------- prep split
// dst row = [hi(512) | slotA(512) | slotB(512)] per off_hi2/off_lo params:
//   A: hi at {0,512}, lo at 1024    B: hi at {0,1024}, lo at 512
__global__ __launch_bounds__(128) void prep_split(const float* __restrict__ src,
                                                  _Float16* __restrict__ dst,
                                                  int off_hi2, int off_lo) {
    const long r = blockIdx.x;
    const int d = threadIdx.x * 4;
    const float4 v = *(const float4*)(src + r * DIM + d);
    f16x4 h, lo;
    h[0] = (_Float16)v.x; h[1] = (_Float16)v.y;
    h[2] = (_Float16)v.z; h[3] = (_Float16)v.w;
    lo[0] = (_Float16)(v.x - (float)h[0]);
    lo[1] = (_Float16)(v.y - (float)h[1]);
    lo[2] = (_Float16)(v.z - (float)h[2]);
    lo[3] = (_Float16)(v.w - (float)h[3]);
    _Float16* base = dst + r * K3;
    *(f16x4*)(base + d) = h;
    *(f16x4*)(base + off_hi2 + d) = h;
    *(f16x4*)(base + off_lo + d) = lo;
}

// ---------------------------------------------------------------- cnorm
__global__ __launch_bounds__(128) void cnorm_kernel(const float* __restrict__ cb,
                                                    float* __restrict__ cnorm) {
    const int k = blockIdx.x;
    const int t = threadIdx.x;
    const float4 v = *(const float4*)(cb + (size_t)k * DIM + t * 4);
    float s = v.x * v.x + v.y * v.y + v.z * v.z + v.w * v.w;
#pragma unroll
    for (int o = 32; o > 0; o >>= 1) s += __shfl_down(s, o, 64);
    __shared__ float red[2];
    if ((t & 63) == 0) red[t >> 6] = s;
    __syncthreads();
    if (t == 0) cnorm[k] = red[0] + red[1];
}

// ---------------------------------------------------------------- score GEMM
// m97-structure: 128x128 tile, BK=64, global_load_lds w=16, 4 waves 2x2,
// each wave 64x64 via 4x4 of 16x16x32 f16 MFMA. Block loops 4 code tiles
// (one 512-code split), keeps per-lane top-2 (val,idx) per point-slot.
// Epilogue: intra-wave 16-lane reduce -> LDS [point][half] -> inter-wave
// merge (waves sharing rows cover DIFFERENT code columns -> must merge,
// not race on the same addresses).
__global__ __launch_bounds__(256) void score_kernel(
    const _Float16* __restrict__ A3, const _Float16* __restrict__ B3,
    const float* __restrict__ cnorm,
    float* __restrict__ pv1, int* __restrict__ pi1,
    float* __restrict__ pv2, int* __restrict__ pi2) {
    __shared__ _Float16 As[128 * 64];   // 16 KB, row-major [point][k]
    __shared__ _Float16 Bs[128 * 64];   // 16 KB, row-major [code][k]
    __shared__ float mv1[128][2], mv2[128][2];   // epilogue merge buffers
    __shared__ int   mj1[128][2], mj2[128][2];   // (+4 KB)

    const int tid = threadIdx.x;
    const int w = tid >> 6;             // wave 0..3
    const int l = tid & 63;
    const int pbase = blockIdx.x * 128;
    const int nsplit = blockIdx.y;      // 0..15
    const int wmb = (w >> 1) * 64;      // wave m offset in tile
    const int wnb = (w & 1) * 64;       // wave n offset in tile
    const int srow = w * 8 + (l >> 3);  // staging row (+ it*32)
    const int scolh = (l & 7) * 8;      // staging col in halfs (16 B)

    float v1[16], v2[16];
    int i1[16], i2[16];
#pragma unroll
    for (int s = 0; s < 16; ++s) { v1[s] = 3.0e38f; v2[s] = 3.0e38f; i1[s] = 0; i2[s] = 0; }

#pragma unroll 1
    for (int nt = 0; nt < 4; ++nt) {
        const int kbase = nsplit * 512 + nt * 128;   // code row base
        f32x4 acc[4][4];
#pragma unroll
        for (int mi = 0; mi < 4; ++mi)
#pragma unroll
            for (int ni = 0; ni < 4; ++ni)
                acc[mi][ni] = (f32x4){0.f, 0.f, 0.f, 0.f};

#pragma unroll 1
        for (int kt = 0; kt < K3 / 64; ++kt) {       // 24 iterations
            const long ka = (long)kt * 64;
            __syncthreads();                          // LDS reuse guard
#pragma unroll
            for (int it = 0; it < 4; ++it) {
                const _Float16* ga = A3 + (long)(pbase + it * 32 + srow) * K3 + ka + scolh;
                GLOAD_LDS16(ga, &As[it * 2048 + w * 512]);
            }
#pragma unroll
            for (int it = 0; it < 4; ++it) {
                const _Float16* gb = B3 + (long)(kbase + it * 32 + srow) * K3 + ka + scolh;
                GLOAD_LDS16(gb, &Bs[it * 2048 + w * 512]);
            }
            __syncthreads();                          // drains vmcnt for glds
#pragma unroll
            for (int ks = 0; ks < 2; ++ks) {
                const int ko = ks * 32 + (l >> 4) * 8;
                half8 af[4], bf[4];
#pragma unroll
                for (int mi = 0; mi < 4; ++mi)
                    af[mi] = *(half8*)&As[(wmb + mi * 16 + (l & 15)) * 64 + ko];
#pragma unroll
                for (int ni = 0; ni < 4; ++ni)
                    bf[ni] = *(half8*)&Bs[(wnb + ni * 16 + (l & 15)) * 64 + ko];
#pragma unroll
                for (int mi = 0; mi < 4; ++mi)
#pragma unroll
                    for (int ni = 0; ni < 4; ++ni)
                        acc[mi][ni] = __builtin_amdgcn_mfma_f32_16x16x32_f16(
                            af[mi], bf[ni], acc[mi][ni], 0, 0, 0);
            }
        }
        // fold this tile's scores into per-lane top2 (codes ascend with nt, ni)
#pragma unroll
        for (int ni = 0; ni < 4; ++ni) {
            const int k = kbase + wnb + ni * 16 + (l & 15);
            const float cn = cnorm[k];
#pragma unroll
            for (int mi = 0; mi < 4; ++mi)
#pragma unroll
                for (int r = 0; r < 4; ++r) {
                    const float s = cn - 2.0f * acc[mi][ni][r];
                    const int slot = mi * 4 + r;
                    if (s < v1[slot]) {
                        v2[slot] = v1[slot]; i2[slot] = i1[slot];
                        v1[slot] = s; i1[slot] = k;
                    } else if (s < v2[slot]) {
                        v2[slot] = s; i2[slot] = k;
                    }
                }
        }
    }

    // cross-lane top2 reduce over the 16 lanes sharing each point row,
    // then deposit per (point, column-half) into LDS
#pragma unroll
    for (int slot = 0; slot < 16; ++slot) {
        float a1 = v1[slot], a2 = v2[slot];
        int b1 = i1[slot], b2 = i2[slot];
#pragma unroll
        for (int m = 1; m < 16; m <<= 1) {
            const float c1 = __shfl_xor(a1, m, 64);
            const int   d1 = __shfl_xor(b1, m, 64);
            const float c2 = __shfl_xor(a2, m, 64);
            const int   d2 = __shfl_xor(b2, m, 64);
            if (c1 < a1 || (c1 == a1 && d1 < b1)) {
                if (a1 < c2 || (a1 == c2 && b1 < d2)) { a2 = a1; b2 = b1; }
                else { a2 = c2; b2 = d2; }
                a1 = c1; b1 = d1;
            } else {
                if (c1 < a2 || (c1 == a2 && d1 < b2)) { a2 = c1; b2 = d1; }
            }
        }
        if ((l & 15) == 0) {
            const int sm = slot >> 2, sr = slot & 3;
            const int pr = wmb + sm * 16 + (l >> 4) * 4 + sr;  // 0..127
            const int h = w & 1;                               // column half
            mv1[pr][h] = a1; mj1[pr][h] = b1;
            mv2[pr][h] = a2; mj2[pr][h] = b2;
        }
    }
    __syncthreads();
    // merge the two column-halves per point; single global write
    if (tid < 128) {
        float a1 = mv1[tid][0], a2 = mv2[tid][0];
        int b1 = mj1[tid][0], b2 = mj2[tid][0];
        const float c1 = mv1[tid][1], c2 = mv2[tid][1];
        const int   d1 = mj1[tid][1], d2 = mj2[tid][1];
        if (c1 < a1 || (c1 == a1 && d1 < b1)) {
            if (a1 < c2 || (a1 == c2 && b1 < d2)) { a2 = a1; b2 = b1; }
            else { a2 = c2; b2 = d2; }
            a1 = c1; b1 = d1;
        } else {
            if (c1 < a2 || (c1 == a2 && d1 < b2)) { a2 = c1; b2 = d1; }
        }
        const size_t o = (size_t)nsplit * N_PTS + pbase + tid;
        pv1[o] = a1; pi1[o] = b1; pv2[o] = a2; pi2[o] = b2;
    }
}

// ---------------------------------------------------------------- merge
__global__ __launch_bounds__(256) void merge_kernel(
    const float* __restrict__ pv1, const int* __restrict__ pi1,
    const float* __restrict__ pv2, const int* __restrict__ pi2,
    int* __restrict__ final_idx, int* __restrict__ resc_count,
    RescEntry* __restrict__ resc_list) {
    const int p = blockIdx.x * 256 + threadIdx.x;
    float bv = 3.0e38f; int bi = 0x7fffffff;
#pragma unroll
    for (int s = 0; s < NSPLIT; ++s) {
        const float v = pv1[(size_t)s * N_PTS + p];
        const int i = pi1[(size_t)s * N_PTS + p];
        if (v < bv || (v == bv && i < bi)) { bv = v; bi = i; }
    }
    float second = 3.0e38f;
    int cand[6]; int nc = 1; cand[0] = bi;
#pragma unroll
    for (int s = 0; s < NSPLIT; ++s) {
        const float v = pv1[(size_t)s * N_PTS + p];
        const int i = pi1[(size_t)s * N_PTS + p];
        const float w = pv2[(size_t)s * N_PTS + p];
        const int j = pi2[(size_t)s * N_PTS + p];
        if (i != bi) {
            if (v < second) second = v;
            if (v <= bv + MARGIN && nc < 6) cand[nc++] = i;
        }
        if (j != bi) {
            if (w < second) second = w;
            if (w <= bv + MARGIN && nc < 6) cand[nc++] = j;
        }
    }
    final_idx[p] = bi;
    if (second - bv <= MARGIN && nc > 1) {
        const int slot = atomicAdd(resc_count, 1);
        if (slot < 4096) {
            RescEntry e; e.p = p; e.n = nc;
#pragma unroll
            for (int q = 0; q < 6; ++q) e.cand[q] = (q < nc) ? cand[q] : bi;
            resc_list[slot] = e;
        }
    }
}

// ---------------------------------------------------------------- rescore
// exact fp64 score for near-tie candidates; overwrites final_idx
__global__ __launch_bounds__(256) void rescore_kernel(
    const float* __restrict__ z_e, const float* __restrict__ cb,
    const RescEntry* __restrict__ resc_list, const int* __restrict__ resc_count,
    int* __restrict__ final_idx) {
    __shared__ double red[4];
    const int t = threadIdx.x;
    int cnt = *resc_count; if (cnt > 4096) cnt = 4096;
    for (int e = blockIdx.x; e < cnt; e += gridDim.x) {
        const RescEntry en = resc_list[e];
        double bestv = 1.0e300; int besti = 0x7fffffff;
        for (int c = 0; c < en.n; ++c) {
            const int k = en.cand[c];
            double part = 0.0;
#pragma unroll
            for (int j = 0; j < 2; ++j) {
                const int d = t * 2 + j;
                const double cv = (double)cb[(size_t)k * DIM + d];
                const double zv = (double)z_e[(size_t)en.p * DIM + d];
                part += cv * cv - 2.0 * zv * cv;
            }
#pragma unroll
            for (int o = 32; o > 0; o >>= 1) part += __shfl_down(part, o, 64);
            if ((t & 63) == 0) red[t >> 6] = part;
            __syncthreads();
            const double s = red[0] + red[1] + red[2] + red[3];
            __syncthreads();
            if (s < bestv || (s == bestv && k < besti)) { bestv = s; besti = k; }
        }
        if (t == 0) final_idx[en.p] = besti;
    }
}

// ---------------------------------------------------------------- gather
__global__ __launch_bounds__(128) void gather_kernel(
    const float* __restrict__ z_e, const float* __restrict__ cb,
    const int* __restrict__ final_idx,
    float* __restrict__ out_q, float* __restrict__ out_idx,
    unsigned int* __restrict__ counts, float* __restrict__ psums) {
    const int p = blockIdx.x;
    const int t = threadIdx.x;
    const int bi = final_idx[p];
    const float4 z = *(const float4*)(z_e + (size_t)p * DIM + t * 4);
    const float4 c = *(const float4*)(cb + (size_t)bi * DIM + t * 4);
    float4 d, o;
    d.x = c.x - z.x; d.y = c.y - z.y; d.z = c.z - z.z; d.w = c.w - z.w;
    o.x = z.x + d.x; o.y = z.y + d.y; o.z = z.z + d.z; o.w = z.w + d.w;
    *(float4*)(out_q + (size_t)p * DIM + t * 4) = o;
    float ls = d.x * d.x + d.y * d.y + d.z * d.z + d.w * d.w;
#pragma unroll
    for (int off = 32; off > 0; off >>= 1) ls += __shfl_down(ls, off, 64);
    __shared__ float red[2];
    if ((t & 63) == 0) red[t >> 6] = ls;
    __syncthreads();
    if (t == 0) {
        psums[p] = red[0] + red[1];
        out_idx[p] = (float)bi;
        atomicAdd(&counts[bi], 1u);
    }
}

// ---------------------------------------------------------------- finalize
__global__ __launch_bounds__(256) void finalize_kernel(
    const unsigned int* __restrict__ counts, const float* __restrict__ psums,
    float* __restrict__ out_scalars) {
    const int t = threadIdx.x;
    float ent = 0.0f;
    for (int b = t; b < K_CODES; b += 256) {
        const float pr = (float)counts[b] * (1.0f / 16384.0f);
        ent += pr * logf(pr + 1e-10f);
    }
    float ss = 0.0f;
    for (int i = t; i < N_PTS; i += 256) ss += psums[i];
#pragma unroll
    for (int off = 32; off > 0; off >>= 1) {
        ent += __shfl_down(ent, off, 64);
        ss += __shfl_down(ss, off, 64);
    }
    __shared__ float re[4], rs[4];
    if ((t & 63) == 0) { re[t >> 6] = ent; rs[t >> 6] = ss; }
    __syncthreads();
    if (t == 0) {
        const float loss = (rs[0] + rs[1] + rs[2] + rs[3]) * (1.0f / NELEM_F);
        out_scalars[0] = loss;
        out_scalars[1] = loss;
        out_scalars[2] = expf(-(re[0] + re[1] + re[2] + re[3]));
    }
}

// ================================================================ fallback
// round-1 pure fp32 path (used only if ws_size < WS_NEED)
#define FB_SPLIT 4
#define FB_KS    (K_CODES / FB_SPLIT)
#define FB_MT    128
#define FB_KT    128
#define FB_DT    32
#define FB_PITCH 36

__global__ __launch_bounds__(256, 2) void fb_dist_argmin_kernel(
    const float* __restrict__ z_e, const float* __restrict__ cb,
    const float* __restrict__ cnorm,
    float* __restrict__ pmin, int* __restrict__ pidx) {
    __shared__ float xs[FB_MT * FB_PITCH];
    __shared__ float cs[FB_KT * FB_PITCH];
    const int tid = threadIdx.x;
    const int tx = tid & 15, ty = tid >> 4;
    const int pbase = blockIdx.x * FB_MT;
    const int kbase0 = blockIdx.y * FB_KS;
    const int scol = (tid & 7) * 4, srow0 = tid >> 3;
    float mn[8], acc[8][8];
    int mi[8];
#pragma unroll
    for (int i = 0; i < 8; ++i) { mn[i] = 3.0e38f; mi[i] = 0; }
    for (int kt = 0; kt < FB_KS / FB_KT; ++kt) {
        const int kbase = kbase0 + kt * FB_KT;
#pragma unroll
        for (int i = 0; i < 8; ++i)
#pragma unroll
            for (int j = 0; j < 8; ++j) acc[i][j] = 0.0f;
        for (int dc = 0; dc < DIM / FB_DT; ++dc) {
            const int dbase = dc * FB_DT;
            __syncthreads();
#pragma unroll
            for (int it = 0; it < 4; ++it) {
                const int row = srow0 + it * 32;
                *(float4*)(xs + row * FB_PITCH + scol) =
                    *(const float4*)(z_e + (size_t)(pbase + row) * DIM + dbase + scol);
                *(float4*)(cs + row * FB_PITCH + scol) =
                    *(const float4*)(cb + (size_t)(kbase + row) * DIM + dbase + scol);
            }
            __syncthreads();
#pragma unroll 2
            for (int dd = 0; dd < FB_DT; dd += 4) {
                float4 xv[8], cv[8];
#pragma unroll
                for (int i = 0; i < 8; ++i)
                    xv[i] = *(const float4*)(xs + (ty + 16 * i) * FB_PITCH + dd);
#pragma unroll
                for (int j = 0; j < 8; ++j)
                    cv[j] = *(const float4*)(cs + (tx + 16 * j) * FB_PITCH + dd);
#pragma unroll
                for (int i = 0; i < 8; ++i)
#pragma unroll
                    for (int j = 0; j < 8; ++j)
                        acc[i][j] += xv[i].x * cv[j].x + xv[i].y * cv[j].y +
                                     xv[i].z * cv[j].z + xv[i].w * cv[j].w;
            }
        }
#pragma unroll
        for (int j = 0; j < 8; ++j) {
            const int k = kbase + tx + 16 * j;
            const float cn = cnorm[k];
#pragma unroll
            for (int i = 0; i < 8; ++i) {
                const float s = cn - 2.0f * acc[i][j];
                if (s < mn[i]) { mn[i] = s; mi[i] = k; }
            }
        }
    }
    float* rmin = xs;
    int* ridx = (int*)cs;
    __syncthreads();
#pragma unroll
    for (int i = 0; i < 8; ++i) {
        const int p = ty + 16 * i;
        rmin[p * 16 + tx] = mn[i];
        ridx[p * 16 + tx] = mi[i];
    }
    __syncthreads();
    if (tid < FB_MT) {
        float best = rmin[tid * 16];
        int bi = ridx[tid * 16];
#pragma unroll
        for (int t = 1; t < 16; ++t) {
            const float v = rmin[tid * 16 + t];
            const int k2 = ridx[tid * 16 + t];
            if (v < best || (v == best && k2 < bi)) { best = v; bi = k2; }
        }
        pmin[(size_t)blockIdx.y * N_PTS + pbase + tid] = best;
        pidx[(size_t)blockIdx.y * N_PTS + pbase + tid] = bi;
    }
}

__global__ __launch_bounds__(128) void fb_gather_kernel(
    const float* __restrict__ z_e, const float* __restrict__ cb,
    const float* __restrict__ pmin, const int* __restrict__ pidx,
    float* __restrict__ out_q, float* __restrict__ out_idx,
    unsigned int* __restrict__ counts, float* __restrict__ psums) {
    const int p = blockIdx.x;
    const int t = threadIdx.x;
    float best = pmin[p];
    int bi = pidx[p];
#pragma unroll
    for (int s = 1; s < FB_SPLIT; ++s) {
        const float v = pmin[(size_t)s * N_PTS + p];
        const int k2 = pidx[(size_t)s * N_PTS + p];
        if (v < best || (v == best && k2 < bi)) { best = v; bi = k2; }
    }
    const float4 z = *(const float4*)(z_e + (size_t)p * DIM + t * 4);
    const float4 c = *(const float4*)(cb + (size_t)bi * DIM + t * 4);
    float4 d, o;
    d.x = c.x - z.x; d.y = c.y - z.y; d.z = c.z - z.z; d.w = c.w - z.w;
    o.x = z.x + d.x; o.y = z.y + d.y; o.z = z.z + d.z; o.w = z.w + d.w;
    *(float4*)(out_q + (size_t)p * DIM + t * 4) = o;
    float ls = d.x * d.x + d.y * d.y + d.z * d.z + d.w * d.w;
#pragma unroll
    for (int off = 32; off > 0; off >>= 1) ls += __shfl_down(ls, off, 64);
    __shared__ float red[2];
    if ((t & 63) == 0) red[t >> 6] = ls;
    __syncthreads();
    if (t == 0) {
        psums[p] = red[0] + red[1];
        out_idx[p] = (float)bi;
        atomicAdd(&counts[bi], 1u);
    }
}

// ================================================================ launch
extern "C" void kernel_launch(void* const* d_in, const int* in_sizes, int n_in,
                              void* d_out, int out_size, void* d_ws, size_t ws_size,
                              hipStream_t stream) {
    const float* z_e = (const float*)d_in[0];
    const float* cb  = (const float*)d_in[1];
    float* out = (float*)d_out;
    char* ws = (char*)d_ws;

    if (ws_size >= WS_NEED) {
        _Float16* A3      = (_Float16*)(ws + OFF_A3);
        _Float16* B3      = (_Float16*)(ws + OFF_B3);
        float* cnorm      = (float*)(ws + OFF_CN);
        float* pv1        = (float*)(ws + OFF_PV1);
        int* pi1          = (int*)(ws + OFF_PI1);
        float* pv2        = (float*)(ws + OFF_PV2);
        int* pi2          = (int*)(ws + OFF_PI2);
        int* final_idx    = (int*)(ws + OFF_FIN);
        float* psums      = (float*)(ws + OFF_PSUM);
        unsigned int* cnt = (unsigned int*)(ws + OFF_CNT);
        int* resc_count   = (int*)(ws + OFF_RCNT);
        RescEntry* rlist  = (RescEntry*)(ws + OFF_RLST);

        hipMemsetAsync(cnt, 0, 32768 + 256, stream);   // counts + resc_count
        prep_split<<<N_PTS, 128, 0, stream>>>(z_e, A3, 512, 1024);   // A:[hi|hi|lo]
        prep_split<<<K_CODES, 128, 0, stream>>>(cb, B3, 1024, 512);  // B:[hi|lo|hi]
        cnorm_kernel<<<K_CODES, 128, 0, stream>>>(cb, cnorm);
        dim3 g(N_PTS / 128, NSPLIT);                   // 128 x 16 blocks
        score_kernel<<<g, 256, 0, stream>>>(A3, B3, cnorm, pv1, pi1, pv2, pi2);
        merge_kernel<<<N_PTS / 256, 256, 0, stream>>>(pv1, pi1, pv2, pi2,
                                                      final_idx, resc_count, rlist);
        rescore_kernel<<<32, 256, 0, stream>>>(z_e, cb, rlist, resc_count, final_idx);
        gather_kernel<<<N_PTS, 128, 0, stream>>>(z_e, cb, final_idx,
                                                 out, out + OUT0_N, cnt, psums);
        finalize_kernel<<<1, 256, 0, stream>>>(cnt, psums, out + OUT0_N + N_PTS);
    } else {
        // round-1 fp32 fallback (<700 KB ws)
        float* cnorm      = (float*)ws;
        float* pmin       = (float*)(ws + 32768);
        int* pidx         = (int*)(ws + 32768 + 262144);
        unsigned int* cnt = (unsigned int*)(ws + 32768 + 2 * 262144);
        float* psums      = (float*)(ws + 32768 + 2 * 262144 + 32768);

        hipMemsetAsync(cnt, 0, 32768, stream);
        cnorm_kernel<<<K_CODES, 128, 0, stream>>>(cb, cnorm);
        dim3 grid1(N_PTS / FB_MT, FB_SPLIT);
        fb_dist_argmin_kernel<<<grid1, 256, 0, stream>>>(z_e, cb, cnorm, pmin, pidx);
        fb_gather_kernel<<<N_PTS, 128, 0, stream>>>(z_e, cb, pmin, pidx,
                                                    out, out + OUT0_N, cnt, psums);
        finalize_kernel<<<1, 256, 0, stream>>>(cnt, psums, out + OUT0_N + N_PTS);
    }
}

// Round 4
// 710.917 us; speedup vs baseline: 3.1579x; 2.2415x over previous
//
#include <hip/hip_runtime.h>

// ---------------------------------------------------------------------------
// VectorQuantizer: N=16384 points x K=8192 codes x D=512 fp32.
// Fast path: fp16 split (hi+lo) GEMM on MFMA with augmented K'=1536
//   dot = hi.hi + hi.lo + lo.hi  (error ~2e-6, lo.lo ~2^-22 dropped)
// Fused top-2 argmin epilogue (inter-wave LDS merge) + fp64 rescore of
// near-ties (margin 3e-3).
// R4: launch_bounds(256,2) [fix 1-wave/SIMD occupancy], XOR-swizzled LDS
// [fix 16-way bank conflicts], NSPLIT 16->8 [halve A re-fetch].
// Fallback (small ws): round-1 pure-fp32 VALU kernel (known-correct).
// ---------------------------------------------------------------------------

#define N_PTS   16384
#define DIM     512
#define K_CODES 8192
#define K3      1536                  // augmented K'
#define NSPLIT  8                     // code splits (1024 codes each)
#define OUT0_N  (N_PTS * DIM)
#define NELEM_F (8388608.0f)
#define MARGIN  3.0e-3f

typedef _Float16 half8 __attribute__((ext_vector_type(8)));
typedef _Float16 f16x4 __attribute__((ext_vector_type(4)));
typedef float    f32x4 __attribute__((ext_vector_type(4)));

struct RescEntry { int p; int n; int cand[6]; };

// fast-path workspace layout (bytes) — kept identical to round 3 (slack ok)
#define SZ_A3    (16384UL * 1536 * 2)              // 50331648
#define SZ_B3    (8192UL * 1536 * 2)               // 25165824
#define OFF_A3   0UL
#define OFF_B3   (OFF_A3 + SZ_A3)
#define OFF_CN   (OFF_B3 + SZ_B3)                  // cnorm 32 KB
#define OFF_PV1  (OFF_CN + 32768UL)
#define SZ_P     (16UL * 16384 * 4)                // 1 MB each (>= NSPLIT*N)
#define OFF_PI1  (OFF_PV1 + SZ_P)
#define OFF_PV2  (OFF_PI1 + SZ_P)
#define OFF_PI2  (OFF_PV2 + SZ_P)
#define OFF_FIN  (OFF_PI2 + SZ_P)                  // final_idx 64 KB
#define OFF_PSUM (OFF_FIN + 65536UL)               // psums 64 KB
#define OFF_CNT  (OFF_PSUM + 65536UL)              // counts 32 KB
#define OFF_RCNT (OFF_CNT + 32768UL)               // resc_count (pad 256)
#define OFF_RLST (OFF_RCNT + 256UL)                // 4096 * 32 B
#define WS_NEED  (OFF_RLST + 4096UL * 32UL)

#define GLOAD_LDS16(g, l) \
    __builtin_amdgcn_global_load_lds( \
        (const __attribute__((address_space(1))) unsigned int*)(g), \
        (__attribute__((address_space(3))) unsigned int*)(l), 16, 0, 0)

// ---------------------------------------------------------------- prep split
// dst row = [hi(512) | slotA(512) | slotB(512)] per off_hi2/off_lo params:
//   A: hi at {0,512}, lo at 1024    B: hi at {0,1024}, lo at 512
__global__ __launch_bounds__(128) void prep_split(const float* __restrict__ src,
                                                  _Float16* __restrict__ dst,
                                                  int off_hi2, int off_lo) {
    const long r = blockIdx.x;
    const int d = threadIdx.x * 4;
    const float4 v = *(const float4*)(src + r * DIM + d);
    f16x4 h, lo;
    h[0] = (_Float16)v.x; h[1] = (_Float16)v.y;
    h[2] = (_Float16)v.z; h[3] = (_Float16)v.w;
    lo[0] = (_Float16)(v.x - (float)h[0]);
    lo[1] = (_Float16)(v.y - (float)h[1]);
    lo[2] = (_Float16)(v.z - (float)h[2]);
    lo[3] = (_Float16)(v.w - (float)h[3]);
    _Float16* base = dst + r * K3;
    *(f16x4*)(base + d) = h;
    *(f16x4*)(base + off_hi2 + d) = h;
    *(f16x4*)(base + off_lo + d) = lo;
}

// ---------------------------------------------------------------- cnorm
__global__ __launch_bounds__(128) void cnorm_kernel(const float* __restrict__ cb,
                                                    float* __restrict__ cnorm) {
    const int k = blockIdx.x;
    const int t = threadIdx.x;
    const float4 v = *(const float4*)(cb + (size_t)k * DIM + t * 4);
    float s = v.x * v.x + v.y * v.y + v.z * v.z + v.w * v.w;
#pragma unroll
    for (int o = 32; o > 0; o >>= 1) s += __shfl_down(s, o, 64);
    __shared__ float red[2];
    if ((t & 63) == 0) red[t >> 6] = s;
    __syncthreads();
    if (t == 0) cnorm[k] = red[0] + red[1];
}

// ---------------------------------------------------------------- score GEMM
// 128x128 tile, BK=64, global_load_lds w=16, 4 waves 2x2, each wave 64x64
// via 4x4 of 16x16x32 f16 MFMA. Block loops 8 code tiles (one 1024-code
// split), keeps per-lane top-2 (val,idx) per point-slot.
// LDS layout XOR-swizzled at 16B-chunk granularity: chunk (row, c) lives at
// slot (row, c ^ (row&7)). Implemented by permuting each lane's GLOBAL
// source column in the glds (dest is lane-ordered, can't scatter), and
// XOR-ing the read offset. Makes wave b128 reads bank-uniform (8 lanes/bank
// over all 32 banks = min) — round-3 showed 1.5e8 conflict cycles from the
// unswizzled [row][k] layout (bank depended only on k-offset -> 16-way).
__global__ __launch_bounds__(256, 2) void score_kernel(
    const _Float16* __restrict__ A3, const _Float16* __restrict__ B3,
    const float* __restrict__ cnorm,
    float* __restrict__ pv1, int* __restrict__ pi1,
    float* __restrict__ pv2, int* __restrict__ pi2) {
    __shared__ _Float16 As[128 * 64];   // 16 KB, [row][chunk swizzled]
    __shared__ _Float16 Bs[128 * 64];   // 16 KB
    __shared__ float mv1[128][2], mv2[128][2];   // epilogue merge buffers
    __shared__ int   mj1[128][2], mj2[128][2];   // (+4 KB)

    const int tid = threadIdx.x;
    const int w = tid >> 6;             // wave 0..3
    const int l = tid & 63;
    const int pbase = blockIdx.x * 128;
    const int nsplit = blockIdx.y;      // 0..7
    const int wmb = (w >> 1) * 64;      // wave m offset in tile
    const int wnb = (w & 1) * 64;       // wave n offset in tile
    const int srow = w * 8 + (l >> 3);  // staging row (+ it*32)
    // swizzled staging source column (halves): lane in slot (row, l&7)
    // must carry global chunk (l&7) ^ (row&7); row&7 == (l>>3)&7 here.
    const int scolh = (((l & 7) ^ ((l >> 3) & 7)) * 8);

    // hoisted row base pointers (kt-invariant; B adds kbase*K3 per nt)
    const _Float16* aB[4];
    const _Float16* bR[4];
#pragma unroll
    for (int it = 0; it < 4; ++it) {
        aB[it] = A3 + (long)(pbase + it * 32 + srow) * K3 + scolh;
        bR[it] = B3 + (long)(it * 32 + srow) * K3 + scolh;
    }

    // fragment-read swizzle pieces (kt/nt-invariant)
    const int q = l >> 4, x7 = l & 7, m16 = l & 15;
    const int koff0 = ((q ^ x7) * 8);          // ks=0 chunk offset (halves)
    const int rowAf = (wmb + m16) * 64;        // + mi*1024
    const int rowBf = (wnb + m16) * 64;        // + ni*1024

    float v1[16], v2[16];
    int i1[16], i2[16];
#pragma unroll
    for (int s = 0; s < 16; ++s) { v1[s] = 3.0e38f; v2[s] = 3.0e38f; i1[s] = 0; i2[s] = 0; }

#pragma unroll 1
    for (int nt = 0; nt < 8; ++nt) {
        const int kbase = nsplit * 1024 + nt * 128;   // code row base
        const long bOff = (long)kbase * K3;
        f32x4 acc[4][4];
#pragma unroll
        for (int mi = 0; mi < 4; ++mi)
#pragma unroll
            for (int ni = 0; ni < 4; ++ni)
                acc[mi][ni] = (f32x4){0.f, 0.f, 0.f, 0.f};

#pragma unroll 1
        for (int kt = 0; kt < K3 / 64; ++kt) {       // 24 iterations
            const long ka = (long)kt * 64;
            __syncthreads();                          // LDS reuse guard
#pragma unroll
            for (int it = 0; it < 4; ++it)
                GLOAD_LDS16(aB[it] + ka, &As[it * 2048 + w * 512]);
#pragma unroll
            for (int it = 0; it < 4; ++it)
                GLOAD_LDS16(bR[it] + bOff + ka, &Bs[it * 2048 + w * 512]);
            __syncthreads();                          // drains vmcnt for glds
#pragma unroll
            for (int ks = 0; ks < 2; ++ks) {
                const int ko = koff0 ^ (ks * 32);     // chunk ^= 4 per ks
                half8 af[4], bf[4];
#pragma unroll
                for (int mi = 0; mi < 4; ++mi)
                    af[mi] = *(half8*)&As[rowAf + mi * 1024 + ko];
#pragma unroll
                for (int ni = 0; ni < 4; ++ni)
                    bf[ni] = *(half8*)&Bs[rowBf + ni * 1024 + ko];
#pragma unroll
                for (int mi = 0; mi < 4; ++mi)
#pragma unroll
                    for (int ni = 0; ni < 4; ++ni)
                        acc[mi][ni] = __builtin_amdgcn_mfma_f32_16x16x32_f16(
                            af[mi], bf[ni], acc[mi][ni], 0, 0, 0);
            }
        }
        // fold this tile's scores into per-lane top2
#pragma unroll
        for (int ni = 0; ni < 4; ++ni) {
            const int k = kbase + wnb + ni * 16 + m16;
            const float cn = cnorm[k];
#pragma unroll
            for (int mi = 0; mi < 4; ++mi)
#pragma unroll
                for (int r = 0; r < 4; ++r) {
                    const float s = cn - 2.0f * acc[mi][ni][r];
                    const int slot = mi * 4 + r;
                    if (s < v1[slot]) {
                        v2[slot] = v1[slot]; i2[slot] = i1[slot];
                        v1[slot] = s; i1[slot] = k;
                    } else if (s < v2[slot]) {
                        v2[slot] = s; i2[slot] = k;
                    }
                }
        }
    }

    // cross-lane top2 reduce over the 16 lanes sharing each point row,
    // then deposit per (point, column-half) into LDS
#pragma unroll
    for (int slot = 0; slot < 16; ++slot) {
        float a1 = v1[slot], a2 = v2[slot];
        int b1 = i1[slot], b2 = i2[slot];
#pragma unroll
        for (int m = 1; m < 16; m <<= 1) {
            const float c1 = __shfl_xor(a1, m, 64);
            const int   d1 = __shfl_xor(b1, m, 64);
            const float c2 = __shfl_xor(a2, m, 64);
            const int   d2 = __shfl_xor(b2, m, 64);
            if (c1 < a1 || (c1 == a1 && d1 < b1)) {
                if (a1 < c2 || (a1 == c2 && b1 < d2)) { a2 = a1; b2 = b1; }
                else { a2 = c2; b2 = d2; }
                a1 = c1; b1 = d1;
            } else {
                if (c1 < a2 || (c1 == a2 && d1 < b2)) { a2 = c1; b2 = d1; }
            }
        }
        if ((l & 15) == 0) {
            const int sm = slot >> 2, sr = slot & 3;
            const int pr = wmb + sm * 16 + (l >> 4) * 4 + sr;  // 0..127
            const int h = w & 1;                               // column half
            mv1[pr][h] = a1; mj1[pr][h] = b1;
            mv2[pr][h] = a2; mj2[pr][h] = b2;
        }
    }
    __syncthreads();
    // merge the two column-halves per point; single global write
    if (tid < 128) {
        float a1 = mv1[tid][0], a2 = mv2[tid][0];
        int b1 = mj1[tid][0], b2 = mj2[tid][0];
        const float c1 = mv1[tid][1], c2 = mv2[tid][1];
        const int   d1 = mj1[tid][1], d2 = mj2[tid][1];
        if (c1 < a1 || (c1 == a1 && d1 < b1)) {
            if (a1 < c2 || (a1 == c2 && b1 < d2)) { a2 = a1; b2 = b1; }
            else { a2 = c2; b2 = d2; }
            a1 = c1; b1 = d1;
        } else {
            if (c1 < a2 || (c1 == a2 && d1 < b2)) { a2 = c1; b2 = d1; }
        }
        const size_t o = (size_t)nsplit * N_PTS + pbase + tid;
        pv1[o] = a1; pi1[o] = b1; pv2[o] = a2; pi2[o] = b2;
    }
}

// ---------------------------------------------------------------- merge
__global__ __launch_bounds__(256) void merge_kernel(
    const float* __restrict__ pv1, const int* __restrict__ pi1,
    const float* __restrict__ pv2, const int* __restrict__ pi2,
    int* __restrict__ final_idx, int* __restrict__ resc_count,
    RescEntry* __restrict__ resc_list) {
    const int p = blockIdx.x * 256 + threadIdx.x;
    float bv = 3.0e38f; int bi = 0x7fffffff;
#pragma unroll
    for (int s = 0; s < NSPLIT; ++s) {
        const float v = pv1[(size_t)s * N_PTS + p];
        const int i = pi1[(size_t)s * N_PTS + p];
        if (v < bv || (v == bv && i < bi)) { bv = v; bi = i; }
    }
    float second = 3.0e38f;
    int cand[6]; int nc = 1; cand[0] = bi;
#pragma unroll
    for (int s = 0; s < NSPLIT; ++s) {
        const float v = pv1[(size_t)s * N_PTS + p];
        const int i = pi1[(size_t)s * N_PTS + p];
        const float w = pv2[(size_t)s * N_PTS + p];
        const int j = pi2[(size_t)s * N_PTS + p];
        if (i != bi) {
            if (v < second) second = v;
            if (v <= bv + MARGIN && nc < 6) cand[nc++] = i;
        }
        if (j != bi) {
            if (w < second) second = w;
            if (w <= bv + MARGIN && nc < 6) cand[nc++] = j;
        }
    }
    final_idx[p] = bi;
    if (second - bv <= MARGIN && nc > 1) {
        const int slot = atomicAdd(resc_count, 1);
        if (slot < 4096) {
            RescEntry e; e.p = p; e.n = nc;
#pragma unroll
            for (int q = 0; q < 6; ++q) e.cand[q] = (q < nc) ? cand[q] : bi;
            resc_list[slot] = e;
        }
    }
}

// ---------------------------------------------------------------- rescore
// exact fp64 score for near-tie candidates; overwrites final_idx
__global__ __launch_bounds__(256) void rescore_kernel(
    const float* __restrict__ z_e, const float* __restrict__ cb,
    const RescEntry* __restrict__ resc_list, const int* __restrict__ resc_count,
    int* __restrict__ final_idx) {
    __shared__ double red[4];
    const int t = threadIdx.x;
    int cnt = *resc_count; if (cnt > 4096) cnt = 4096;
    for (int e = blockIdx.x; e < cnt; e += gridDim.x) {
        const RescEntry en = resc_list[e];
        double bestv = 1.0e300; int besti = 0x7fffffff;
        for (int c = 0; c < en.n; ++c) {
            const int k = en.cand[c];
            double part = 0.0;
#pragma unroll
            for (int j = 0; j < 2; ++j) {
                const int d = t * 2 + j;
                const double cv = (double)cb[(size_t)k * DIM + d];
                const double zv = (double)z_e[(size_t)en.p * DIM + d];
                part += cv * cv - 2.0 * zv * cv;
            }
#pragma unroll
            for (int o = 32; o > 0; o >>= 1) part += __shfl_down(part, o, 64);
            if ((t & 63) == 0) red[t >> 6] = part;
            __syncthreads();
            const double s = red[0] + red[1] + red[2] + red[3];
            __syncthreads();
            if (s < bestv || (s == bestv && k < besti)) { bestv = s; besti = k; }
        }
        if (t == 0) final_idx[en.p] = besti;
    }
}

// ---------------------------------------------------------------- gather
__global__ __launch_bounds__(128) void gather_kernel(
    const float* __restrict__ z_e, const float* __restrict__ cb,
    const int* __restrict__ final_idx,
    float* __restrict__ out_q, float* __restrict__ out_idx,
    unsigned int* __restrict__ counts, float* __restrict__ psums) {
    const int p = blockIdx.x;
    const int t = threadIdx.x;
    const int bi = final_idx[p];
    const float4 z = *(const float4*)(z_e + (size_t)p * DIM + t * 4);
    const float4 c = *(const float4*)(cb + (size_t)bi * DIM + t * 4);
    float4 d, o;
    d.x = c.x - z.x; d.y = c.y - z.y; d.z = c.z - z.z; d.w = c.w - z.w;
    o.x = z.x + d.x; o.y = z.y + d.y; o.z = z.z + d.z; o.w = z.w + d.w;
    *(float4*)(out_q + (size_t)p * DIM + t * 4) = o;
    float ls = d.x * d.x + d.y * d.y + d.z * d.z + d.w * d.w;
#pragma unroll
    for (int off = 32; off > 0; off >>= 1) ls += __shfl_down(ls, off, 64);
    __shared__ float red[2];
    if ((t & 63) == 0) red[t >> 6] = ls;
    __syncthreads();
    if (t == 0) {
        psums[p] = red[0] + red[1];
        out_idx[p] = (float)bi;
        atomicAdd(&counts[bi], 1u);
    }
}

// ---------------------------------------------------------------- finalize
__global__ __launch_bounds__(256) void finalize_kernel(
    const unsigned int* __restrict__ counts, const float* __restrict__ psums,
    float* __restrict__ out_scalars) {
    const int t = threadIdx.x;
    float ent = 0.0f;
    for (int b = t; b < K_CODES; b += 256) {
        const float pr = (float)counts[b] * (1.0f / 16384.0f);
        ent += pr * logf(pr + 1e-10f);
    }
    float ss = 0.0f;
    for (int i = t; i < N_PTS; i += 256) ss += psums[i];
#pragma unroll
    for (int off = 32; off > 0; off >>= 1) {
        ent += __shfl_down(ent, off, 64);
        ss += __shfl_down(ss, off, 64);
    }
    __shared__ float re[4], rs[4];
    if ((t & 63) == 0) { re[t >> 6] = ent; rs[t >> 6] = ss; }
    __syncthreads();
    if (t == 0) {
        const float loss = (rs[0] + rs[1] + rs[2] + rs[3]) * (1.0f / NELEM_F);
        out_scalars[0] = loss;
        out_scalars[1] = loss;
        out_scalars[2] = expf(-(re[0] + re[1] + re[2] + re[3]));
    }
}

// ================================================================ fallback
// round-1 pure fp32 path (used only if ws_size < WS_NEED)
#define FB_SPLIT 4
#define FB_KS    (K_CODES / FB_SPLIT)
#define FB_MT    128
#define FB_KT    128
#define FB_DT    32
#define FB_PITCH 36

__global__ __launch_bounds__(256, 2) void fb_dist_argmin_kernel(
    const float* __restrict__ z_e, const float* __restrict__ cb,
    const float* __restrict__ cnorm,
    float* __restrict__ pmin, int* __restrict__ pidx) {
    __shared__ float xs[FB_MT * FB_PITCH];
    __shared__ float cs[FB_KT * FB_PITCH];
    const int tid = threadIdx.x;
    const int tx = tid & 15, ty = tid >> 4;
    const int pbase = blockIdx.x * FB_MT;
    const int kbase0 = blockIdx.y * FB_KS;
    const int scol = (tid & 7) * 4, srow0 = tid >> 3;
    float mn[8], acc[8][8];
    int mi[8];
#pragma unroll
    for (int i = 0; i < 8; ++i) { mn[i] = 3.0e38f; mi[i] = 0; }
    for (int kt = 0; kt < FB_KS / FB_KT; ++kt) {
        const int kbase = kbase0 + kt * FB_KT;
#pragma unroll
        for (int i = 0; i < 8; ++i)
#pragma unroll
            for (int j = 0; j < 8; ++j) acc[i][j] = 0.0f;
        for (int dc = 0; dc < DIM / FB_DT; ++dc) {
            const int dbase = dc * FB_DT;
            __syncthreads();
#pragma unroll
            for (int it = 0; it < 4; ++it) {
                const int row = srow0 + it * 32;
                *(float4*)(xs + row * FB_PITCH + scol) =
                    *(const float4*)(z_e + (size_t)(pbase + row) * DIM + dbase + scol);
                *(float4*)(cs + row * FB_PITCH + scol) =
                    *(const float4*)(cb + (size_t)(kbase + row) * DIM + dbase + scol);
            }
            __syncthreads();
#pragma unroll 2
            for (int dd = 0; dd < FB_DT; dd += 4) {
                float4 xv[8], cv[8];
#pragma unroll
                for (int i = 0; i < 8; ++i)
                    xv[i] = *(const float4*)(xs + (ty + 16 * i) * FB_PITCH + dd);
#pragma unroll
                for (int j = 0; j < 8; ++j)
                    cv[j] = *(const float4*)(cs + (tx + 16 * j) * FB_PITCH + dd);
#pragma unroll
                for (int i = 0; i < 8; ++i)
#pragma unroll
                    for (int j = 0; j < 8; ++j)
                        acc[i][j] += xv[i].x * cv[j].x + xv[i].y * cv[j].y +
                                     xv[i].z * cv[j].z + xv[i].w * cv[j].w;
            }
        }
#pragma unroll
        for (int j = 0; j < 8; ++j) {
            const int k = kbase + tx + 16 * j;
            const float cn = cnorm[k];
#pragma unroll
            for (int i = 0; i < 8; ++i) {
                const float s = cn - 2.0f * acc[i][j];
                if (s < mn[i]) { mn[i] = s; mi[i] = k; }
            }
        }
    }
    float* rmin = xs;
    int* ridx = (int*)cs;
    __syncthreads();
#pragma unroll
    for (int i = 0; i < 8; ++i) {
        const int p = ty + 16 * i;
        rmin[p * 16 + tx] = mn[i];
        ridx[p * 16 + tx] = mi[i];
    }
    __syncthreads();
    if (tid < FB_MT) {
        float best = rmin[tid * 16];
        int bi = ridx[tid * 16];
#pragma unroll
        for (int t = 1; t < 16; ++t) {
            const float v = rmin[tid * 16 + t];
            const int k2 = ridx[tid * 16 + t];
            if (v < best || (v == best && k2 < bi)) { best = v; bi = k2; }
        }
        pmin[(size_t)blockIdx.y * N_PTS + pbase + tid] = best;
        pidx[(size_t)blockIdx.y * N_PTS + pbase + tid] = bi;
    }
}

__global__ __launch_bounds__(128) void fb_gather_kernel(
    const float* __restrict__ z_e, const float* __restrict__ cb,
    const float* __restrict__ pmin, const int* __restrict__ pidx,
    float* __restrict__ out_q, float* __restrict__ out_idx,
    unsigned int* __restrict__ counts, float* __restrict__ psums) {
    const int p = blockIdx.x;
    const int t = threadIdx.x;
    float best = pmin[p];
    int bi = pidx[p];
#pragma unroll
    for (int s = 1; s < FB_SPLIT; ++s) {
        const float v = pmin[(size_t)s * N_PTS + p];
        const int k2 = pidx[(size_t)s * N_PTS + p];
        if (v < best || (v == best && k2 < bi)) { best = v; bi = k2; }
    }
    const float4 z = *(const float4*)(z_e + (size_t)p * DIM + t * 4);
    const float4 c = *(const float4*)(cb + (size_t)bi * DIM + t * 4);
    float4 d, o;
    d.x = c.x - z.x; d.y = c.y - z.y; d.z = c.z - z.z; d.w = c.w - z.w;
    o.x = z.x + d.x; o.y = z.y + d.y; o.z = z.z + d.z; o.w = z.w + d.w;
    *(float4*)(out_q + (size_t)p * DIM + t * 4) = o;
    float ls = d.x * d.x + d.y * d.y + d.z * d.z + d.w * d.w;
#pragma unroll
    for (int off = 32; off > 0; off >>= 1) ls += __shfl_down(ls, off, 64);
    __shared__ float red[2];
    if ((t & 63) == 0) red[t >> 6] = ls;
    __syncthreads();
    if (t == 0) {
        psums[p] = red[0] + red[1];
        out_idx[p] = (float)bi;
        atomicAdd(&counts[bi], 1u);
    }
}

// ================================================================ launch
extern "C" void kernel_launch(void* const* d_in, const int* in_sizes, int n_in,
                              void* d_out, int out_size, void* d_ws, size_t ws_size,
                              hipStream_t stream) {
    const float* z_e = (const float*)d_in[0];
    const float* cb  = (const float*)d_in[1];
    float* out = (float*)d_out;
    char* ws = (char*)d_ws;

    if (ws_size >= WS_NEED) {
        _Float16* A3      = (_Float16*)(ws + OFF_A3);
        _Float16* B3      = (_Float16*)(ws + OFF_B3);
        float* cnorm      = (float*)(ws + OFF_CN);
        float* pv1        = (float*)(ws + OFF_PV1);
        int* pi1          = (int*)(ws + OFF_PI1);
        float* pv2        = (float*)(ws + OFF_PV2);
        int* pi2          = (int*)(ws + OFF_PI2);
        int* final_idx    = (int*)(ws + OFF_FIN);
        float* psums      = (float*)(ws + OFF_PSUM);
        unsigned int* cnt = (unsigned int*)(ws + OFF_CNT);
        int* resc_count   = (int*)(ws + OFF_RCNT);
        RescEntry* rlist  = (RescEntry*)(ws + OFF_RLST);

        hipMemsetAsync(cnt, 0, 32768 + 256, stream);   // counts + resc_count
        prep_split<<<N_PTS, 128, 0, stream>>>(z_e, A3, 512, 1024);   // A:[hi|hi|lo]
        prep_split<<<K_CODES, 128, 0, stream>>>(cb, B3, 1024, 512);  // B:[hi|lo|hi]
        cnorm_kernel<<<K_CODES, 128, 0, stream>>>(cb, cnorm);
        dim3 g(N_PTS / 128, NSPLIT);                   // 128 x 8 blocks
        score_kernel<<<g, 256, 0, stream>>>(A3, B3, cnorm, pv1, pi1, pv2, pi2);
        merge_kernel<<<N_PTS / 256, 256, 0, stream>>>(pv1, pi1, pv2, pi2,
                                                      final_idx, resc_count, rlist);
        rescore_kernel<<<32, 256, 0, stream>>>(z_e, cb, rlist, resc_count, final_idx);
        gather_kernel<<<N_PTS, 128, 0, stream>>>(z_e, cb, final_idx,
                                                 out, out + OUT0_N, cnt, psums);
        finalize_kernel<<<1, 256, 0, stream>>>(cnt, psums, out + OUT0_N + N_PTS);
    } else {
        // round-1 fp32 fallback (<700 KB ws)
        float* cnorm      = (float*)ws;
        float* pmin       = (float*)(ws + 32768);
        int* pidx         = (int*)(ws + 32768 + 262144);
        unsigned int* cnt = (unsigned int*)(ws + 32768 + 2 * 262144);
        float* psums      = (float*)(ws + 32768 + 2 * 262144 + 32768);

        hipMemsetAsync(cnt, 0, 32768, stream);
        cnorm_kernel<<<K_CODES, 128, 0, stream>>>(cb, cnorm);
        dim3 grid1(N_PTS / FB_MT, FB_SPLIT);
        fb_dist_argmin_kernel<<<grid1, 256, 0, stream>>>(z_e, cb, cnorm, pmin, pidx);
        fb_gather_kernel<<<N_PTS, 128, 0, stream>>>(z_e, cb, pmin, pidx,
                                                    out, out + OUT0_N, cnt, psums);
        finalize_kernel<<<1, 256, 0, stream>>>(cnt, psums, out + OUT0_N + N_PTS);
    }
}

// Round 5
// 482.706 us; speedup vs baseline: 4.6509x; 1.4728x over previous
//
#include <hip/hip_runtime.h>

// ---------------------------------------------------------------------------
// VectorQuantizer: N=16384 points x K=8192 codes x D=512 fp32.
// Fast path (R5): fp16 one-sided-split GEMM, K'=1024:
//   dot ~= h_x.h_c + h_x.l_c   (A'=[h|h] stored once w/ ka&511 re-read trick,
//   B'=[h_c|l_c]; dropped l_x.h_c has sigma~4e-4 << 3e-3 fp64-rescore margin)
// Fused top-2 argmin epilogue (XOR-swizzled LDS, packed 16-bit idx pairs,
// launch_bounds(256,3) for 3 waves/SIMD) + fp64 rescore of near-ties.
// Fallback (small ws): round-1 pure-fp32 VALU kernel (known-correct).
// ---------------------------------------------------------------------------

#define N_PTS   16384
#define DIM     512
#define K_CODES 8192
#define KB      1024                  // augmented K'
#define NSPLIT  16                    // code splits (512 codes each)
#define OUT0_N  (N_PTS * DIM)
#define NELEM_F (8388608.0f)
#define MARGIN  3.0e-3f

typedef _Float16 half8 __attribute__((ext_vector_type(8)));
typedef _Float16 f16x4 __attribute__((ext_vector_type(4)));
typedef float    f32x4 __attribute__((ext_vector_type(4)));

struct RescEntry { int p; int n; int cand[6]; };

// fast-path workspace layout (bytes)
#define SZ_A3    (16384UL * 512 * 2)               // 16.8 MB (hi only)
#define SZ_B3    (8192UL * 1024 * 2)               // 16.8 MB ([hi|lo])
#define OFF_A3   0UL
#define OFF_B3   (OFF_A3 + SZ_A3)
#define OFF_CN   (OFF_B3 + SZ_B3)                  // cnorm 32 KB
#define OFF_PV1  (OFF_CN + 32768UL)
#define SZ_P     (16UL * 16384 * 4)                // 1 MB each
#define OFF_PI1  (OFF_PV1 + SZ_P)
#define OFF_PV2  (OFF_PI1 + SZ_P)
#define OFF_PI2  (OFF_PV2 + SZ_P)
#define OFF_FIN  (OFF_PI2 + SZ_P)                  // final_idx 64 KB
#define OFF_PSUM (OFF_FIN + 65536UL)               // psums 64 KB
#define OFF_CNT  (OFF_PSUM + 65536UL)              // counts 32 KB
#define OFF_RCNT (OFF_CNT + 32768UL)               // resc_count (pad 256)
#define OFF_RLST (OFF_RCNT + 256UL)                // 4096 * 32 B
#define WS_NEED  (OFF_RLST + 4096UL * 32UL)

#define GLOAD_LDS16(g, l) \
    __builtin_amdgcn_global_load_lds( \
        (const __attribute__((address_space(1))) unsigned int*)(g), \
        (__attribute__((address_space(3))) unsigned int*)(l), 16, 0, 0)

// ---------------------------------------------------------------- prep A
// A3 row = hi(512) only (fp16 cast of z_e row)
__global__ __launch_bounds__(128) void prep_a(const float* __restrict__ src,
                                              _Float16* __restrict__ dst) {
    const long r = blockIdx.x;
    const int d = threadIdx.x * 4;
    const float4 v = *(const float4*)(src + r * DIM + d);
    f16x4 h;
    h[0] = (_Float16)v.x; h[1] = (_Float16)v.y;
    h[2] = (_Float16)v.z; h[3] = (_Float16)v.w;
    *(f16x4*)(dst + r * 512 + d) = h;
}

// ---------------------------------------------------------------- prep B
// B3 row = [hi(512) | lo(512)]
__global__ __launch_bounds__(128) void prep_b(const float* __restrict__ src,
                                              _Float16* __restrict__ dst) {
    const long r = blockIdx.x;
    const int d = threadIdx.x * 4;
    const float4 v = *(const float4*)(src + r * DIM + d);
    f16x4 h, lo;
    h[0] = (_Float16)v.x; h[1] = (_Float16)v.y;
    h[2] = (_Float16)v.z; h[3] = (_Float16)v.w;
    lo[0] = (_Float16)(v.x - (float)h[0]);
    lo[1] = (_Float16)(v.y - (float)h[1]);
    lo[2] = (_Float16)(v.z - (float)h[2]);
    lo[3] = (_Float16)(v.w - (float)h[3]);
    _Float16* base = dst + r * 1024;
    *(f16x4*)(base + d) = h;
    *(f16x4*)(base + 512 + d) = lo;
}

// ---------------------------------------------------------------- cnorm
__global__ __launch_bounds__(128) void cnorm_kernel(const float* __restrict__ cb,
                                                    float* __restrict__ cnorm) {
    const int k = blockIdx.x;
    const int t = threadIdx.x;
    const float4 v = *(const float4*)(cb + (size_t)k * DIM + t * 4);
    float s = v.x * v.x + v.y * v.y + v.z * v.z + v.w * v.w;
#pragma unroll
    for (int o = 32; o > 0; o >>= 1) s += __shfl_down(s, o, 64);
    __shared__ float red[2];
    if ((t & 63) == 0) red[t >> 6] = s;
    __syncthreads();
    if (t == 0) cnorm[k] = red[0] + red[1];
}

// ---------------------------------------------------------------- score GEMM
// 128x128 tile, BK=64, global_load_lds w=16, 4 waves 2x2, each wave 64x64
// via 4x4 of 16x16x32 f16 MFMA. Block loops 4 code tiles (one 512-code
// split) over K'=1024; A source column = ka & 511 (hi duplicated on the fly).
// LDS XOR-swizzled at 16B-chunk granularity (R4: conflicts -> 0).
// Top-2 (val, packed idx) per point-slot; inter-wave LDS merge epilogue.
__global__ __launch_bounds__(256, 3) void score_kernel(
    const _Float16* __restrict__ A3, const _Float16* __restrict__ B3,
    const float* __restrict__ cnorm,
    float* __restrict__ pv1, int* __restrict__ pi1,
    float* __restrict__ pv2, int* __restrict__ pi2) {
    __shared__ _Float16 As[128 * 64];   // 16 KB
    __shared__ _Float16 Bs[128 * 64];   // 16 KB
    __shared__ float mv1[128][2], mv2[128][2];
    __shared__ int   mj1[128][2], mj2[128][2];

    const int tid = threadIdx.x;
    const int w = tid >> 6;             // wave 0..3
    const int l = tid & 63;
    const int pbase = blockIdx.x * 128;
    const int nsplit = blockIdx.y;      // 0..15
    const int wmb = (w >> 1) * 64;      // wave m offset
    const int wnb = (w & 1) * 64;       // wave n offset
    const int srow = w * 8 + (l >> 3);  // staging row (+ it*32)
    const int scolh = (((l & 7) ^ ((l >> 3) & 7)) * 8);   // swizzled src col

    // hoisted row base pointers
    const _Float16* aB[4];
    const _Float16* bR[4];
#pragma unroll
    for (int it = 0; it < 4; ++it) {
        aB[it] = A3 + (long)(pbase + it * 32 + srow) * 512 + scolh;
        bR[it] = B3 + (long)(it * 32 + srow) * 1024 + scolh;
    }

    const int q = l >> 4, x7 = l & 7, m16 = l & 15;
    const int koff0 = ((q ^ x7) * 8);          // ks=0 chunk offset (halves)
    const int rowAf = (wmb + m16) * 64;        // + mi*1024
    const int rowBf = (wnb + m16) * 64;        // + ni*1024

    float v1[16], v2[16];
    int i12[16];                               // (i1<<16) | i2, codes < 8192
#pragma unroll
    for (int s = 0; s < 16; ++s) { v1[s] = 3.0e38f; v2[s] = 3.0e38f; i12[s] = 0; }

#pragma unroll 1
    for (int nt = 0; nt < 4; ++nt) {
        const int kbase = nsplit * 512 + nt * 128;   // code row base
        const long bOff = (long)kbase * 1024;
        f32x4 acc[4][4];
#pragma unroll
        for (int mi = 0; mi < 4; ++mi)
#pragma unroll
            for (int ni = 0; ni < 4; ++ni)
                acc[mi][ni] = (f32x4){0.f, 0.f, 0.f, 0.f};

#pragma unroll 1
        for (int kt = 0; kt < KB / 64; ++kt) {       // 16 iterations
            const long ka = (long)kt * 64;
            const long kaA = ka & 511;               // hi duplicated for k'>=512
            __syncthreads();                          // LDS reuse guard
#pragma unroll
            for (int it = 0; it < 4; ++it)
                GLOAD_LDS16(aB[it] + kaA, &As[it * 2048 + w * 512]);
#pragma unroll
            for (int it = 0; it < 4; ++it)
                GLOAD_LDS16(bR[it] + bOff + ka, &Bs[it * 2048 + w * 512]);
            __syncthreads();                          // drains vmcnt for glds
#pragma unroll
            for (int ks = 0; ks < 2; ++ks) {
                const int ko = koff0 ^ (ks * 32);
                half8 af[4], bf[4];
#pragma unroll
                for (int mi = 0; mi < 4; ++mi)
                    af[mi] = *(half8*)&As[rowAf + mi * 1024 + ko];
#pragma unroll
                for (int ni = 0; ni < 4; ++ni)
                    bf[ni] = *(half8*)&Bs[rowBf + ni * 1024 + ko];
#pragma unroll
                for (int mi = 0; mi < 4; ++mi)
#pragma unroll
                    for (int ni = 0; ni < 4; ++ni)
                        acc[mi][ni] = __builtin_amdgcn_mfma_f32_16x16x32_f16(
                            af[mi], bf[ni], acc[mi][ni], 0, 0, 0);
            }
        }
        // fold this tile's scores into per-lane top2
#pragma unroll
        for (int ni = 0; ni < 4; ++ni) {
            const int k = kbase + wnb + ni * 16 + m16;
            const float cn = cnorm[k];
#pragma unroll
            for (int mi = 0; mi < 4; ++mi)
#pragma unroll
                for (int r = 0; r < 4; ++r) {
                    const float s = fmaf(-2.0f, acc[mi][ni][r], cn);
                    const int slot = mi * 4 + r;
                    if (s < v1[slot]) {               // strict <: lowest k wins
                        v2[slot] = v1[slot];
                        i12[slot] = (k << 16) | (i12[slot] >> 16);
                        v1[slot] = s;
                    } else if (s < v2[slot]) {
                        v2[slot] = s;
                        i12[slot] = (i12[slot] & 0xffff0000) | k;
                    }
                }
        }
    }

    // cross-lane top2 reduce over the 16 lanes sharing each point row,
    // deposit per (point, column-half) into LDS
#pragma unroll
    for (int slot = 0; slot < 16; ++slot) {
        float a1 = v1[slot], a2 = v2[slot];
        int b1 = i12[slot] >> 16, b2 = i12[slot] & 0xffff;
#pragma unroll
        for (int m = 1; m < 16; m <<= 1) {
            const float c1 = __shfl_xor(a1, m, 64);
            const int   d1 = __shfl_xor(b1, m, 64);
            const float c2 = __shfl_xor(a2, m, 64);
            const int   d2 = __shfl_xor(b2, m, 64);
            if (c1 < a1 || (c1 == a1 && d1 < b1)) {
                if (a1 < c2 || (a1 == c2 && b1 < d2)) { a2 = a1; b2 = b1; }
                else { a2 = c2; b2 = d2; }
                a1 = c1; b1 = d1;
            } else {
                if (c1 < a2 || (c1 == a2 && d1 < b2)) { a2 = c1; b2 = d1; }
            }
        }
        if ((l & 15) == 0) {
            const int sm = slot >> 2, sr = slot & 3;
            const int pr = wmb + sm * 16 + (l >> 4) * 4 + sr;  // 0..127
            const int h = w & 1;                               // column half
            mv1[pr][h] = a1; mj1[pr][h] = b1;
            mv2[pr][h] = a2; mj2[pr][h] = b2;
        }
    }
    __syncthreads();
    // merge the two column-halves per point; single global write
    if (tid < 128) {
        float a1 = mv1[tid][0], a2 = mv2[tid][0];
        int b1 = mj1[tid][0], b2 = mj2[tid][0];
        const float c1 = mv1[tid][1], c2 = mv2[tid][1];
        const int   d1 = mj1[tid][1], d2 = mj2[tid][1];
        if (c1 < a1 || (c1 == a1 && d1 < b1)) {
            if (a1 < c2 || (a1 == c2 && b1 < d2)) { a2 = a1; b2 = b1; }
            else { a2 = c2; b2 = d2; }
            a1 = c1; b1 = d1;
        } else {
            if (c1 < a2 || (c1 == a2 && d1 < b2)) { a2 = c1; b2 = d1; }
        }
        const size_t o = (size_t)nsplit * N_PTS + pbase + tid;
        pv1[o] = a1; pi1[o] = b1; pv2[o] = a2; pi2[o] = b2;
    }
}

// ---------------------------------------------------------------- merge
__global__ __launch_bounds__(256) void merge_kernel(
    const float* __restrict__ pv1, const int* __restrict__ pi1,
    const float* __restrict__ pv2, const int* __restrict__ pi2,
    int* __restrict__ final_idx, int* __restrict__ resc_count,
    RescEntry* __restrict__ resc_list) {
    const int p = blockIdx.x * 256 + threadIdx.x;
    float bv = 3.0e38f; int bi = 0x7fffffff;
#pragma unroll
    for (int s = 0; s < NSPLIT; ++s) {
        const float v = pv1[(size_t)s * N_PTS + p];
        const int i = pi1[(size_t)s * N_PTS + p];
        if (v < bv || (v == bv && i < bi)) { bv = v; bi = i; }
    }
    float second = 3.0e38f;
    int cand[6]; int nc = 1; cand[0] = bi;
#pragma unroll
    for (int s = 0; s < NSPLIT; ++s) {
        const float v = pv1[(size_t)s * N_PTS + p];
        const int i = pi1[(size_t)s * N_PTS + p];
        const float w = pv2[(size_t)s * N_PTS + p];
        const int j = pi2[(size_t)s * N_PTS + p];
        if (i != bi) {
            if (v < second) second = v;
            if (v <= bv + MARGIN && nc < 6) cand[nc++] = i;
        }
        if (j != bi) {
            if (w < second) second = w;
            if (w <= bv + MARGIN && nc < 6) cand[nc++] = j;
        }
    }
    final_idx[p] = bi;
    if (second - bv <= MARGIN && nc > 1) {
        const int slot = atomicAdd(resc_count, 1);
        if (slot < 4096) {
            RescEntry e; e.p = p; e.n = nc;
#pragma unroll
            for (int q = 0; q < 6; ++q) e.cand[q] = (q < nc) ? cand[q] : bi;
            resc_list[slot] = e;
        }
    }
}

// ---------------------------------------------------------------- rescore
// exact fp64 score for near-tie candidates; overwrites final_idx
__global__ __launch_bounds__(256) void rescore_kernel(
    const float* __restrict__ z_e, const float* __restrict__ cb,
    const RescEntry* __restrict__ resc_list, const int* __restrict__ resc_count,
    int* __restrict__ final_idx) {
    __shared__ double red[4];
    const int t = threadIdx.x;
    int cnt = *resc_count; if (cnt > 4096) cnt = 4096;
    for (int e = blockIdx.x; e < cnt; e += gridDim.x) {
        const RescEntry en = resc_list[e];
        double bestv = 1.0e300; int besti = 0x7fffffff;
        for (int c = 0; c < en.n; ++c) {
            const int k = en.cand[c];
            double part = 0.0;
#pragma unroll
            for (int j = 0; j < 2; ++j) {
                const int d = t * 2 + j;
                const double cv = (double)cb[(size_t)k * DIM + d];
                const double zv = (double)z_e[(size_t)en.p * DIM + d];
                part += cv * cv - 2.0 * zv * cv;
            }
#pragma unroll
            for (int o = 32; o > 0; o >>= 1) part += __shfl_down(part, o, 64);
            if ((t & 63) == 0) red[t >> 6] = part;
            __syncthreads();
            const double s = red[0] + red[1] + red[2] + red[3];
            __syncthreads();
            if (s < bestv || (s == bestv && k < besti)) { bestv = s; besti = k; }
        }
        if (t == 0) final_idx[en.p] = besti;
    }
}

// ---------------------------------------------------------------- gather
__global__ __launch_bounds__(128) void gather_kernel(
    const float* __restrict__ z_e, const float* __restrict__ cb,
    const int* __restrict__ final_idx,
    float* __restrict__ out_q, float* __restrict__ out_idx,
    unsigned int* __restrict__ counts, float* __restrict__ psums) {
    const int p = blockIdx.x;
    const int t = threadIdx.x;
    const int bi = final_idx[p];
    const float4 z = *(const float4*)(z_e + (size_t)p * DIM + t * 4);
    const float4 c = *(const float4*)(cb + (size_t)bi * DIM + t * 4);
    float4 d, o;
    d.x = c.x - z.x; d.y = c.y - z.y; d.z = c.z - z.z; d.w = c.w - z.w;
    o.x = z.x + d.x; o.y = z.y + d.y; o.z = z.z + d.z; o.w = z.w + d.w;
    *(float4*)(out_q + (size_t)p * DIM + t * 4) = o;
    float ls = d.x * d.x + d.y * d.y + d.z * d.z + d.w * d.w;
#pragma unroll
    for (int off = 32; off > 0; off >>= 1) ls += __shfl_down(ls, off, 64);
    __shared__ float red[2];
    if ((t & 63) == 0) red[t >> 6] = ls;
    __syncthreads();
    if (t == 0) {
        psums[p] = red[0] + red[1];
        out_idx[p] = (float)bi;
        atomicAdd(&counts[bi], 1u);
    }
}

// ---------------------------------------------------------------- finalize
__global__ __launch_bounds__(256) void finalize_kernel(
    const unsigned int* __restrict__ counts, const float* __restrict__ psums,
    float* __restrict__ out_scalars) {
    const int t = threadIdx.x;
    float ent = 0.0f;
    for (int b = t; b < K_CODES; b += 256) {
        const float pr = (float)counts[b] * (1.0f / 16384.0f);
        ent += pr * logf(pr + 1e-10f);
    }
    float ss = 0.0f;
    for (int i = t; i < N_PTS; i += 256) ss += psums[i];
#pragma unroll
    for (int off = 32; off > 0; off >>= 1) {
        ent += __shfl_down(ent, off, 64);
        ss += __shfl_down(ss, off, 64);
    }
    __shared__ float re[4], rs[4];
    if ((t & 63) == 0) { re[t >> 6] = ent; rs[t >> 6] = ss; }
    __syncthreads();
    if (t == 0) {
        const float loss = (rs[0] + rs[1] + rs[2] + rs[3]) * (1.0f / NELEM_F);
        out_scalars[0] = loss;
        out_scalars[1] = loss;
        out_scalars[2] = expf(-(re[0] + re[1] + re[2] + re[3]));
    }
}

// ================================================================ fallback
// round-1 pure fp32 path (used only if ws_size < WS_NEED)
#define FB_SPLIT 4
#define FB_KS    (K_CODES / FB_SPLIT)
#define FB_MT    128
#define FB_KT    128
#define FB_DT    32
#define FB_PITCH 36

__global__ __launch_bounds__(256, 2) void fb_dist_argmin_kernel(
    const float* __restrict__ z_e, const float* __restrict__ cb,
    const float* __restrict__ cnorm,
    float* __restrict__ pmin, int* __restrict__ pidx) {
    __shared__ float xs[FB_MT * FB_PITCH];
    __shared__ float cs[FB_KT * FB_PITCH];
    const int tid = threadIdx.x;
    const int tx = tid & 15, ty = tid >> 4;
    const int pbase = blockIdx.x * FB_MT;
    const int kbase0 = blockIdx.y * FB_KS;
    const int scol = (tid & 7) * 4, srow0 = tid >> 3;
    float mn[8], acc[8][8];
    int mi[8];
#pragma unroll
    for (int i = 0; i < 8; ++i) { mn[i] = 3.0e38f; mi[i] = 0; }
    for (int kt = 0; kt < FB_KS / FB_KT; ++kt) {
        const int kbase = kbase0 + kt * FB_KT;
#pragma unroll
        for (int i = 0; i < 8; ++i)
#pragma unroll
            for (int j = 0; j < 8; ++j) acc[i][j] = 0.0f;
        for (int dc = 0; dc < DIM / FB_DT; ++dc) {
            const int dbase = dc * FB_DT;
            __syncthreads();
#pragma unroll
            for (int it = 0; it < 4; ++it) {
                const int row = srow0 + it * 32;
                *(float4*)(xs + row * FB_PITCH + scol) =
                    *(const float4*)(z_e + (size_t)(pbase + row) * DIM + dbase + scol);
                *(float4*)(cs + row * FB_PITCH + scol) =
                    *(const float4*)(cb + (size_t)(kbase + row) * DIM + dbase + scol);
            }
            __syncthreads();
#pragma unroll 2
            for (int dd = 0; dd < FB_DT; dd += 4) {
                float4 xv[8], cv[8];
#pragma unroll
                for (int i = 0; i < 8; ++i)
                    xv[i] = *(const float4*)(xs + (ty + 16 * i) * FB_PITCH + dd);
#pragma unroll
                for (int j = 0; j < 8; ++j)
                    cv[j] = *(const float4*)(cs + (tx + 16 * j) * FB_PITCH + dd);
#pragma unroll
                for (int i = 0; i < 8; ++i)
#pragma unroll
                    for (int j = 0; j < 8; ++j)
                        acc[i][j] += xv[i].x * cv[j].x + xv[i].y * cv[j].y +
                                     xv[i].z * cv[j].z + xv[i].w * cv[j].w;
            }
        }
#pragma unroll
        for (int j = 0; j < 8; ++j) {
            const int k = kbase + tx + 16 * j;
            const float cn = cnorm[k];
#pragma unroll
            for (int i = 0; i < 8; ++i) {
                const float s = cn - 2.0f * acc[i][j];
                if (s < mn[i]) { mn[i] = s; mi[i] = k; }
            }
        }
    }
    float* rmin = xs;
    int* ridx = (int*)cs;
    __syncthreads();
#pragma unroll
    for (int i = 0; i < 8; ++i) {
        const int p = ty + 16 * i;
        rmin[p * 16 + tx] = mn[i];
        ridx[p * 16 + tx] = mi[i];
    }
    __syncthreads();
    if (tid < FB_MT) {
        float best = rmin[tid * 16];
        int bi = ridx[tid * 16];
#pragma unroll
        for (int t = 1; t < 16; ++t) {
            const float v = rmin[tid * 16 + t];
            const int k2 = ridx[tid * 16 + t];
            if (v < best || (v == best && k2 < bi)) { best = v; bi = k2; }
        }
        pmin[(size_t)blockIdx.y * N_PTS + pbase + tid] = best;
        pidx[(size_t)blockIdx.y * N_PTS + pbase + tid] = bi;
    }
}

__global__ __launch_bounds__(128) void fb_gather_kernel(
    const float* __restrict__ z_e, const float* __restrict__ cb,
    const float* __restrict__ pmin, const int* __restrict__ pidx,
    float* __restrict__ out_q, float* __restrict__ out_idx,
    unsigned int* __restrict__ counts, float* __restrict__ psums) {
    const int p = blockIdx.x;
    const int t = threadIdx.x;
    float best = pmin[p];
    int bi = pidx[p];
#pragma unroll
    for (int s = 1; s < FB_SPLIT; ++s) {
        const float v = pmin[(size_t)s * N_PTS + p];
        const int k2 = pidx[(size_t)s * N_PTS + p];
        if (v < best || (v == best && k2 < bi)) { best = v; bi = k2; }
    }
    const float4 z = *(const float4*)(z_e + (size_t)p * DIM + t * 4);
    const float4 c = *(const float4*)(cb + (size_t)bi * DIM + t * 4);
    float4 d, o;
    d.x = c.x - z.x; d.y = c.y - z.y; d.z = c.z - z.z; d.w = c.w - z.w;
    o.x = z.x + d.x; o.y = z.y + d.y; o.z = z.z + d.z; o.w = z.w + d.w;
    *(float4*)(out_q + (size_t)p * DIM + t * 4) = o;
    float ls = d.x * d.x + d.y * d.y + d.z * d.z + d.w * d.w;
#pragma unroll
    for (int off = 32; off > 0; off >>= 1) ls += __shfl_down(ls, off, 64);
    __shared__ float red[2];
    if ((t & 63) == 0) red[t >> 6] = ls;
    __syncthreads();
    if (t == 0) {
        psums[p] = red[0] + red[1];
        out_idx[p] = (float)bi;
        atomicAdd(&counts[bi], 1u);
    }
}

// ================================================================ launch
extern "C" void kernel_launch(void* const* d_in, const int* in_sizes, int n_in,
                              void* d_out, int out_size, void* d_ws, size_t ws_size,
                              hipStream_t stream) {
    const float* z_e = (const float*)d_in[0];
    const float* cb  = (const float*)d_in[1];
    float* out = (float*)d_out;
    char* ws = (char*)d_ws;

    if (ws_size >= WS_NEED) {
        _Float16* A3      = (_Float16*)(ws + OFF_A3);
        _Float16* B3      = (_Float16*)(ws + OFF_B3);
        float* cnorm      = (float*)(ws + OFF_CN);
        float* pv1        = (float*)(ws + OFF_PV1);
        int* pi1          = (int*)(ws + OFF_PI1);
        float* pv2        = (float*)(ws + OFF_PV2);
        int* pi2          = (int*)(ws + OFF_PI2);
        int* final_idx    = (int*)(ws + OFF_FIN);
        float* psums      = (float*)(ws + OFF_PSUM);
        unsigned int* cnt = (unsigned int*)(ws + OFF_CNT);
        int* resc_count   = (int*)(ws + OFF_RCNT);
        RescEntry* rlist  = (RescEntry*)(ws + OFF_RLST);

        hipMemsetAsync(cnt, 0, 32768 + 256, stream);   // counts + resc_count
        prep_a<<<N_PTS, 128, 0, stream>>>(z_e, A3);
        prep_b<<<K_CODES, 128, 0, stream>>>(cb, B3);
        cnorm_kernel<<<K_CODES, 128, 0, stream>>>(cb, cnorm);
        dim3 g(N_PTS / 128, NSPLIT);                   // 128 x 16 blocks
        score_kernel<<<g, 256, 0, stream>>>(A3, B3, cnorm, pv1, pi1, pv2, pi2);
        merge_kernel<<<N_PTS / 256, 256, 0, stream>>>(pv1, pi1, pv2, pi2,
                                                      final_idx, resc_count, rlist);
        rescore_kernel<<<32, 256, 0, stream>>>(z_e, cb, rlist, resc_count, final_idx);
        gather_kernel<<<N_PTS, 128, 0, stream>>>(z_e, cb, final_idx,
                                                 out, out + OUT0_N, cnt, psums);
        finalize_kernel<<<1, 256, 0, stream>>>(cnt, psums, out + OUT0_N + N_PTS);
    } else {
        // round-1 fp32 fallback (<700 KB ws)
        float* cnorm      = (float*)ws;
        float* pmin       = (float*)(ws + 32768);
        int* pidx         = (int*)(ws + 32768 + 262144);
        unsigned int* cnt = (unsigned int*)(ws + 32768 + 2 * 262144);
        float* psums      = (float*)(ws + 32768 + 2 * 262144 + 32768);

        hipMemsetAsync(cnt, 0, 32768, stream);
        cnorm_kernel<<<K_CODES, 128, 0, stream>>>(cb, cnorm);
        dim3 grid1(N_PTS / FB_MT, FB_SPLIT);
        fb_dist_argmin_kernel<<<grid1, 256, 0, stream>>>(z_e, cb, cnorm, pmin, pidx);
        fb_gather_kernel<<<N_PTS, 128, 0, stream>>>(z_e, cb, pmin, pidx,
                                                    out, out + OUT0_N, cnt, psums);
        finalize_kernel<<<1, 256, 0, stream>>>(cnt, psums, out + OUT0_N + N_PTS);
    }
}

// Round 6
// 395.150 us; speedup vs baseline: 5.6814x; 1.2216x over previous
//
#include <hip/hip_runtime.h>

// ---------------------------------------------------------------------------
// VectorQuantizer: N=16384 points x K=8192 codes x D=512 fp32.
// Fast path (R6): pure-fp16 screening GEMM, K'=512 (dot ~= h_x.h_c; both
// dropped cross terms have sigma ~9e-4 << 1.5e-2 margin = 17 sigma), fused
// top-2 argmin epilogue (XOR-swizzled LDS, 0 bank conflicts), then a fused
// gather kernel that merges split partials, fp64-rescores near-ties
// (margin 1.5e-2) and writes all outputs. cnorm fused into prep_b.
// Fallback (small ws): round-1 pure-fp32 VALU kernel (known-correct).
// ---------------------------------------------------------------------------

#define N_PTS   16384
#define DIM     512
#define K_CODES 8192
#define KB      512                   // screening K (hi only)
#define NSPLIT  16                    // code splits (512 codes each)
#define OUT0_N  (N_PTS * DIM)
#define NELEM_F (8388608.0f)
#define MARGIN  1.5e-2f

typedef _Float16 half8 __attribute__((ext_vector_type(8)));
typedef _Float16 f16x4 __attribute__((ext_vector_type(4)));
typedef float    f32x4 __attribute__((ext_vector_type(4)));

// fast-path workspace layout (bytes)
#define SZ_A3    (16384UL * 512 * 2)               // 16.8 MB
#define SZ_B3    (8192UL * 512 * 2)                // 8.4 MB
#define OFF_A3   0UL
#define OFF_B3   (OFF_A3 + SZ_A3)
#define OFF_CN   (OFF_B3 + SZ_B3)                  // cnorm 32 KB
#define OFF_PV1  (OFF_CN + 32768UL)
#define SZ_P     (16UL * 16384 * 4)                // 1 MB each
#define OFF_PI1  (OFF_PV1 + SZ_P)
#define OFF_PV2  (OFF_PI1 + SZ_P)
#define OFF_PI2  (OFF_PV2 + SZ_P)
#define OFF_PSUM (OFF_PI2 + SZ_P)                  // psums 64 KB
#define OFF_CNT  (OFF_PSUM + 65536UL)              // counts 32 KB
#define WS_NEED  (OFF_CNT + 32768UL)

#define GLOAD_LDS16(g, l) \
    __builtin_amdgcn_global_load_lds( \
        (const __attribute__((address_space(1))) unsigned int*)(g), \
        (__attribute__((address_space(3))) unsigned int*)(l), 16, 0, 0)

// ---------------------------------------------------------------- prep A
__global__ __launch_bounds__(128) void prep_a(const float* __restrict__ src,
                                              _Float16* __restrict__ dst) {
    const long r = blockIdx.x;
    const int d = threadIdx.x * 4;
    const float4 v = *(const float4*)(src + r * DIM + d);
    f16x4 h;
    h[0] = (_Float16)v.x; h[1] = (_Float16)v.y;
    h[2] = (_Float16)v.z; h[3] = (_Float16)v.w;
    *(f16x4*)(dst + r * 512 + d) = h;
}

// ---------------------------------------------------------------- prep B + norm
__global__ __launch_bounds__(128) void prep_b_norm(const float* __restrict__ cb,
                                                   _Float16* __restrict__ dst,
                                                   float* __restrict__ cnorm) {
    const long r = blockIdx.x;
    const int t = threadIdx.x;
    const int d = t * 4;
    const float4 v = *(const float4*)(cb + r * DIM + d);
    f16x4 h;
    h[0] = (_Float16)v.x; h[1] = (_Float16)v.y;
    h[2] = (_Float16)v.z; h[3] = (_Float16)v.w;
    *(f16x4*)(dst + r * 512 + d) = h;
    float s = v.x * v.x + v.y * v.y + v.z * v.z + v.w * v.w;
#pragma unroll
    for (int o = 32; o > 0; o >>= 1) s += __shfl_down(s, o, 64);
    __shared__ float red[2];
    if ((t & 63) == 0) red[t >> 6] = s;
    __syncthreads();
    if (t == 0) cnorm[r] = red[0] + red[1];
}

// ---------------------------------------------------------------- cnorm (fallback)
__global__ __launch_bounds__(128) void cnorm_kernel(const float* __restrict__ cb,
                                                    float* __restrict__ cnorm) {
    const int k = blockIdx.x;
    const int t = threadIdx.x;
    const float4 v = *(const float4*)(cb + (size_t)k * DIM + t * 4);
    float s = v.x * v.x + v.y * v.y + v.z * v.z + v.w * v.w;
#pragma unroll
    for (int o = 32; o > 0; o >>= 1) s += __shfl_down(s, o, 64);
    __shared__ float red[2];
    if ((t & 63) == 0) red[t >> 6] = s;
    __syncthreads();
    if (t == 0) cnorm[k] = red[0] + red[1];
}

// ---------------------------------------------------------------- score GEMM
// 128x128 tile, BK=64, global_load_lds w=16, 4 waves 2x2, each wave 64x64
// via 4x4 of 16x16x32 f16 MFMA. Block loops 4 code tiles (one 512-code
// split) over K'=512. LDS XOR-swizzled at 16B-chunk granularity (R4:
// conflicts -> 0). Top-2 (val, packed idx) per point-slot; inter-wave LDS
// merge epilogue (R3 race fix).
__global__ __launch_bounds__(256, 3) void score_kernel(
    const _Float16* __restrict__ A3, const _Float16* __restrict__ B3,
    const float* __restrict__ cnorm,
    float* __restrict__ pv1, int* __restrict__ pi1,
    float* __restrict__ pv2, int* __restrict__ pi2) {
    __shared__ _Float16 As[128 * 64];   // 16 KB
    __shared__ _Float16 Bs[128 * 64];   // 16 KB
    __shared__ float mv1[128][2], mv2[128][2];
    __shared__ int   mj1[128][2], mj2[128][2];

    const int tid = threadIdx.x;
    const int w = tid >> 6;             // wave 0..3
    const int l = tid & 63;
    const int pbase = blockIdx.x * 128;
    const int nsplit = blockIdx.y;      // 0..15
    const int wmb = (w >> 1) * 64;      // wave m offset
    const int wnb = (w & 1) * 64;       // wave n offset
    const int srow = w * 8 + (l >> 3);  // staging row (+ it*32)
    const int scolh = (((l & 7) ^ ((l >> 3) & 7)) * 8);   // swizzled src col

    const _Float16* aB[4];
    const _Float16* bR[4];
#pragma unroll
    for (int it = 0; it < 4; ++it) {
        aB[it] = A3 + (long)(pbase + it * 32 + srow) * 512 + scolh;
        bR[it] = B3 + (long)(it * 32 + srow) * 512 + scolh;
    }

    const int q = l >> 4, x7 = l & 7, m16 = l & 15;
    const int koff0 = ((q ^ x7) * 8);          // ks=0 chunk offset (halves)
    const int rowAf = (wmb + m16) * 64;        // + mi*1024
    const int rowBf = (wnb + m16) * 64;        // + ni*1024

    float v1[16], v2[16];
    int i12[16];                               // (i1<<16) | i2, codes < 8192
#pragma unroll
    for (int s = 0; s < 16; ++s) { v1[s] = 3.0e38f; v2[s] = 3.0e38f; i12[s] = 0; }

#pragma unroll 1
    for (int nt = 0; nt < 4; ++nt) {
        const int kbase = nsplit * 512 + nt * 128;   // code row base
        const long bOff = (long)kbase * 512;
        f32x4 acc[4][4];
#pragma unroll
        for (int mi = 0; mi < 4; ++mi)
#pragma unroll
            for (int ni = 0; ni < 4; ++ni)
                acc[mi][ni] = (f32x4){0.f, 0.f, 0.f, 0.f};

#pragma unroll 1
        for (int kt = 0; kt < KB / 64; ++kt) {       // 8 iterations
            const long ka = (long)kt * 64;
            __syncthreads();                          // LDS reuse guard
#pragma unroll
            for (int it = 0; it < 4; ++it)
                GLOAD_LDS16(aB[it] + ka, &As[it * 2048 + w * 512]);
#pragma unroll
            for (int it = 0; it < 4; ++it)
                GLOAD_LDS16(bR[it] + bOff + ka, &Bs[it * 2048 + w * 512]);
            __syncthreads();                          // drains vmcnt for glds
#pragma unroll
            for (int ks = 0; ks < 2; ++ks) {
                const int ko = koff0 ^ (ks * 32);
                half8 af[4], bf[4];
#pragma unroll
                for (int mi = 0; mi < 4; ++mi)
                    af[mi] = *(half8*)&As[rowAf + mi * 1024 + ko];
#pragma unroll
                for (int ni = 0; ni < 4; ++ni)
                    bf[ni] = *(half8*)&Bs[rowBf + ni * 1024 + ko];
#pragma unroll
                for (int mi = 0; mi < 4; ++mi)
#pragma unroll
                    for (int ni = 0; ni < 4; ++ni)
                        acc[mi][ni] = __builtin_amdgcn_mfma_f32_16x16x32_f16(
                            af[mi], bf[ni], acc[mi][ni], 0, 0, 0);
            }
        }
        // fold this tile's scores into per-lane top2
#pragma unroll
        for (int ni = 0; ni < 4; ++ni) {
            const int k = kbase + wnb + ni * 16 + m16;
            const float cn = cnorm[k];
#pragma unroll
            for (int mi = 0; mi < 4; ++mi)
#pragma unroll
                for (int r = 0; r < 4; ++r) {
                    const float s = fmaf(-2.0f, acc[mi][ni][r], cn);
                    const int slot = mi * 4 + r;
                    if (s < v1[slot]) {               // strict <: lowest k wins
                        v2[slot] = v1[slot];
                        i12[slot] = (k << 16) | (i12[slot] >> 16);
                        v1[slot] = s;
                    } else if (s < v2[slot]) {
                        v2[slot] = s;
                        i12[slot] = (i12[slot] & 0xffff0000) | k;
                    }
                }
        }
    }

    // cross-lane top2 reduce over the 16 lanes sharing each point row,
    // deposit per (point, column-half) into LDS
#pragma unroll
    for (int slot = 0; slot < 16; ++slot) {
        float a1 = v1[slot], a2 = v2[slot];
        int b1 = i12[slot] >> 16, b2 = i12[slot] & 0xffff;
#pragma unroll
        for (int m = 1; m < 16; m <<= 1) {
            const float c1 = __shfl_xor(a1, m, 64);
            const int   d1 = __shfl_xor(b1, m, 64);
            const float c2 = __shfl_xor(a2, m, 64);
            const int   d2 = __shfl_xor(b2, m, 64);
            if (c1 < a1 || (c1 == a1 && d1 < b1)) {
                if (a1 < c2 || (a1 == c2 && b1 < d2)) { a2 = a1; b2 = b1; }
                else { a2 = c2; b2 = d2; }
                a1 = c1; b1 = d1;
            } else {
                if (c1 < a2 || (c1 == a2 && d1 < b2)) { a2 = c1; b2 = d1; }
            }
        }
        if ((l & 15) == 0) {
            const int sm = slot >> 2, sr = slot & 3;
            const int pr = wmb + sm * 16 + (l >> 4) * 4 + sr;  // 0..127
            const int h = w & 1;                               // column half
            mv1[pr][h] = a1; mj1[pr][h] = b1;
            mv2[pr][h] = a2; mj2[pr][h] = b2;
        }
    }
    __syncthreads();
    // merge the two column-halves per point; single global write
    if (tid < 128) {
        float a1 = mv1[tid][0], a2 = mv2[tid][0];
        int b1 = mj1[tid][0], b2 = mj2[tid][0];
        const float c1 = mv1[tid][1], c2 = mv2[tid][1];
        const int   d1 = mj1[tid][1], d2 = mj2[tid][1];
        if (c1 < a1 || (c1 == a1 && d1 < b1)) {
            if (a1 < c2 || (a1 == c2 && b1 < d2)) { a2 = a1; b2 = b1; }
            else { a2 = c2; b2 = d2; }
            a1 = c1; b1 = d1;
        } else {
            if (c1 < a2 || (c1 == a2 && d1 < b2)) { a2 = c1; b2 = d1; }
        }
        const size_t o = (size_t)nsplit * N_PTS + pbase + tid;
        pv1[o] = a1; pi1[o] = b1; pv2[o] = a2; pi2[o] = b2;
    }
}

// ---------------------------------------------------------------- gather
// Fused: merge split partials -> candidate set; fp64 rescore if any rival
// within MARGIN of the noisy best (block-uniform branch); then gather code
// row, write z_q_st / idx / histogram / partial loss.
__global__ __launch_bounds__(128) void gather_kernel(
    const float* __restrict__ z_e, const float* __restrict__ cb,
    const float* __restrict__ pv1, const int* __restrict__ pi1,
    const float* __restrict__ pv2, const int* __restrict__ pi2,
    float* __restrict__ out_q, float* __restrict__ out_idx,
    unsigned int* __restrict__ counts, float* __restrict__ psums) {
    const int p = blockIdx.x;
    const int t = threadIdx.x;

    // merge (redundant across threads; wave-uniform loads)
    float bv = 3.0e38f; int bi = 0x7fffffff;
#pragma unroll
    for (int s = 0; s < NSPLIT; ++s) {
        const float v = pv1[(size_t)s * N_PTS + p];
        const int i = pi1[(size_t)s * N_PTS + p];
        if (v < bv || (v == bv && i < bi)) { bv = v; bi = i; }
    }
    float second = 3.0e38f;
    int cand[8]; int nc = 1; cand[0] = bi;
#pragma unroll
    for (int s = 0; s < NSPLIT; ++s) {
        const float v = pv1[(size_t)s * N_PTS + p];
        const int i = pi1[(size_t)s * N_PTS + p];
        const float w2 = pv2[(size_t)s * N_PTS + p];
        const int j = pi2[(size_t)s * N_PTS + p];
        if (i != bi) {
            if (v < second) second = v;
            if (v <= bv + MARGIN && nc < 8) cand[nc++] = i;
        }
        if (j != bi) {
            if (w2 < second) second = w2;
            if (w2 <= bv + MARGIN && nc < 8) cand[nc++] = j;
        }
    }

    __shared__ double dred[2];
    if (second - bv <= MARGIN && nc > 1) {     // block-uniform condition
        double bestv = 1.0e300; int besti = 0x7fffffff;
        for (int c = 0; c < nc; ++c) {
            const int k = cand[c];
            double part = 0.0;
#pragma unroll
            for (int j = 0; j < 4; ++j) {
                const int d = t * 4 + j;
                const double cv = (double)cb[(size_t)k * DIM + d];
                const double zv = (double)z_e[(size_t)p * DIM + d];
                part += cv * cv - 2.0 * zv * cv;
            }
#pragma unroll
            for (int o = 32; o > 0; o >>= 1) part += __shfl_down(part, o, 64);
            if ((t & 63) == 0) dred[t >> 6] = part;
            __syncthreads();
            const double s = dred[0] + dred[1];
            __syncthreads();
            if (s < bestv || (s == bestv && k < besti)) { bestv = s; besti = k; }
        }
        bi = besti;
    }

    const float4 z = *(const float4*)(z_e + (size_t)p * DIM + t * 4);
    const float4 c = *(const float4*)(cb + (size_t)bi * DIM + t * 4);
    float4 d, o;
    d.x = c.x - z.x; d.y = c.y - z.y; d.z = c.z - z.z; d.w = c.w - z.w;
    o.x = z.x + d.x; o.y = z.y + d.y; o.z = z.z + d.z; o.w = z.w + d.w;
    *(float4*)(out_q + (size_t)p * DIM + t * 4) = o;
    float ls = d.x * d.x + d.y * d.y + d.z * d.z + d.w * d.w;
#pragma unroll
    for (int off = 32; off > 0; off >>= 1) ls += __shfl_down(ls, off, 64);
    __shared__ float red[2];
    if ((t & 63) == 0) red[t >> 6] = ls;
    __syncthreads();
    if (t == 0) {
        psums[p] = red[0] + red[1];
        out_idx[p] = (float)bi;
        atomicAdd(&counts[bi], 1u);
    }
}

// ---------------------------------------------------------------- finalize
__global__ __launch_bounds__(256) void finalize_kernel(
    const unsigned int* __restrict__ counts, const float* __restrict__ psums,
    float* __restrict__ out_scalars) {
    const int t = threadIdx.x;
    float ent = 0.0f;
    for (int b = t; b < K_CODES; b += 256) {
        const float pr = (float)counts[b] * (1.0f / 16384.0f);
        ent += pr * logf(pr + 1e-10f);
    }
    float ss = 0.0f;
    for (int i = t; i < N_PTS; i += 256) ss += psums[i];
#pragma unroll
    for (int off = 32; off > 0; off >>= 1) {
        ent += __shfl_down(ent, off, 64);
        ss += __shfl_down(ss, off, 64);
    }
    __shared__ float re[4], rs[4];
    if ((t & 63) == 0) { re[t >> 6] = ent; rs[t >> 6] = ss; }
    __syncthreads();
    if (t == 0) {
        const float loss = (rs[0] + rs[1] + rs[2] + rs[3]) * (1.0f / NELEM_F);
        out_scalars[0] = loss;
        out_scalars[1] = loss;
        out_scalars[2] = expf(-(re[0] + re[1] + re[2] + re[3]));
    }
}

// ================================================================ fallback
// round-1 pure fp32 path (used only if ws_size < WS_NEED)
#define FB_SPLIT 4
#define FB_KS    (K_CODES / FB_SPLIT)
#define FB_MT    128
#define FB_KT    128
#define FB_DT    32
#define FB_PITCH 36

__global__ __launch_bounds__(256, 2) void fb_dist_argmin_kernel(
    const float* __restrict__ z_e, const float* __restrict__ cb,
    const float* __restrict__ cnorm,
    float* __restrict__ pmin, int* __restrict__ pidx) {
    __shared__ float xs[FB_MT * FB_PITCH];
    __shared__ float cs[FB_KT * FB_PITCH];
    const int tid = threadIdx.x;
    const int tx = tid & 15, ty = tid >> 4;
    const int pbase = blockIdx.x * FB_MT;
    const int kbase0 = blockIdx.y * FB_KS;
    const int scol = (tid & 7) * 4, srow0 = tid >> 3;
    float mn[8], acc[8][8];
    int mi[8];
#pragma unroll
    for (int i = 0; i < 8; ++i) { mn[i] = 3.0e38f; mi[i] = 0; }
    for (int kt = 0; kt < FB_KS / FB_KT; ++kt) {
        const int kbase = kbase0 + kt * FB_KT;
#pragma unroll
        for (int i = 0; i < 8; ++i)
#pragma unroll
            for (int j = 0; j < 8; ++j) acc[i][j] = 0.0f;
        for (int dc = 0; dc < DIM / FB_DT; ++dc) {
            const int dbase = dc * FB_DT;
            __syncthreads();
#pragma unroll
            for (int it = 0; it < 4; ++it) {
                const int row = srow0 + it * 32;
                *(float4*)(xs + row * FB_PITCH + scol) =
                    *(const float4*)(z_e + (size_t)(pbase + row) * DIM + dbase + scol);
                *(float4*)(cs + row * FB_PITCH + scol) =
                    *(const float4*)(cb + (size_t)(kbase + row) * DIM + dbase + scol);
            }
            __syncthreads();
#pragma unroll 2
            for (int dd = 0; dd < FB_DT; dd += 4) {
                float4 xv[8], cv[8];
#pragma unroll
                for (int i = 0; i < 8; ++i)
                    xv[i] = *(const float4*)(xs + (ty + 16 * i) * FB_PITCH + dd);
#pragma unroll
                for (int j = 0; j < 8; ++j)
                    cv[j] = *(const float4*)(cs + (tx + 16 * j) * FB_PITCH + dd);
#pragma unroll
                for (int i = 0; i < 8; ++i)
#pragma unroll
                    for (int j = 0; j < 8; ++j)
                        acc[i][j] += xv[i].x * cv[j].x + xv[i].y * cv[j].y +
                                     xv[i].z * cv[j].z + xv[i].w * cv[j].w;
            }
        }
#pragma unroll
        for (int j = 0; j < 8; ++j) {
            const int k = kbase + tx + 16 * j;
            const float cn = cnorm[k];
#pragma unroll
            for (int i = 0; i < 8; ++i) {
                const float s = cn - 2.0f * acc[i][j];
                if (s < mn[i]) { mn[i] = s; mi[i] = k; }
            }
        }
    }
    float* rmin = xs;
    int* ridx = (int*)cs;
    __syncthreads();
#pragma unroll
    for (int i = 0; i < 8; ++i) {
        const int p = ty + 16 * i;
        rmin[p * 16 + tx] = mn[i];
        ridx[p * 16 + tx] = mi[i];
    }
    __syncthreads();
    if (tid < FB_MT) {
        float best = rmin[tid * 16];
        int bi = ridx[tid * 16];
#pragma unroll
        for (int t = 1; t < 16; ++t) {
            const float v = rmin[tid * 16 + t];
            const int k2 = ridx[tid * 16 + t];
            if (v < best || (v == best && k2 < bi)) { best = v; bi = k2; }
        }
        pmin[(size_t)blockIdx.y * N_PTS + pbase + tid] = best;
        pidx[(size_t)blockIdx.y * N_PTS + pbase + tid] = bi;
    }
}

__global__ __launch_bounds__(128) void fb_gather_kernel(
    const float* __restrict__ z_e, const float* __restrict__ cb,
    const float* __restrict__ pmin, const int* __restrict__ pidx,
    float* __restrict__ out_q, float* __restrict__ out_idx,
    unsigned int* __restrict__ counts, float* __restrict__ psums) {
    const int p = blockIdx.x;
    const int t = threadIdx.x;
    float best = pmin[p];
    int bi = pidx[p];
#pragma unroll
    for (int s = 1; s < FB_SPLIT; ++s) {
        const float v = pmin[(size_t)s * N_PTS + p];
        const int k2 = pidx[(size_t)s * N_PTS + p];
        if (v < best || (v == best && k2 < bi)) { best = v; bi = k2; }
    }
    const float4 z = *(const float4*)(z_e + (size_t)p * DIM + t * 4);
    const float4 c = *(const float4*)(cb + (size_t)bi * DIM + t * 4);
    float4 d, o;
    d.x = c.x - z.x; d.y = c.y - z.y; d.z = c.z - z.z; d.w = c.w - z.w;
    o.x = z.x + d.x; o.y = z.y + d.y; o.z = z.z + d.z; o.w = z.w + d.w;
    *(float4*)(out_q + (size_t)p * DIM + t * 4) = o;
    float ls = d.x * d.x + d.y * d.y + d.z * d.z + d.w * d.w;
#pragma unroll
    for (int off = 32; off > 0; off >>= 1) ls += __shfl_down(ls, off, 64);
    __shared__ float red[2];
    if ((t & 63) == 0) red[t >> 6] = ls;
    __syncthreads();
    if (t == 0) {
        psums[p] = red[0] + red[1];
        out_idx[p] = (float)bi;
        atomicAdd(&counts[bi], 1u);
    }
}

// ================================================================ launch
extern "C" void kernel_launch(void* const* d_in, const int* in_sizes, int n_in,
                              void* d_out, int out_size, void* d_ws, size_t ws_size,
                              hipStream_t stream) {
    const float* z_e = (const float*)d_in[0];
    const float* cb  = (const float*)d_in[1];
    float* out = (float*)d_out;
    char* ws = (char*)d_ws;

    if (ws_size >= WS_NEED) {
        _Float16* A3      = (_Float16*)(ws + OFF_A3);
        _Float16* B3      = (_Float16*)(ws + OFF_B3);
        float* cnorm      = (float*)(ws + OFF_CN);
        float* pv1        = (float*)(ws + OFF_PV1);
        int* pi1          = (int*)(ws + OFF_PI1);
        float* pv2        = (float*)(ws + OFF_PV2);
        int* pi2          = (int*)(ws + OFF_PI2);
        float* psums      = (float*)(ws + OFF_PSUM);
        unsigned int* cnt = (unsigned int*)(ws + OFF_CNT);

        hipMemsetAsync(cnt, 0, 32768, stream);         // histogram counts
        prep_a<<<N_PTS, 128, 0, stream>>>(z_e, A3);
        prep_b_norm<<<K_CODES, 128, 0, stream>>>(cb, B3, cnorm);
        dim3 g(N_PTS / 128, NSPLIT);                   // 128 x 16 blocks
        score_kernel<<<g, 256, 0, stream>>>(A3, B3, cnorm, pv1, pi1, pv2, pi2);
        gather_kernel<<<N_PTS, 128, 0, stream>>>(z_e, cb, pv1, pi1, pv2, pi2,
                                                 out, out + OUT0_N, cnt, psums);
        finalize_kernel<<<1, 256, 0, stream>>>(cnt, psums, out + OUT0_N + N_PTS);
    } else {
        // round-1 fp32 fallback (<700 KB ws)
        float* cnorm      = (float*)ws;
        float* pmin       = (float*)(ws + 32768);
        int* pidx         = (int*)(ws + 32768 + 262144);
        unsigned int* cnt = (unsigned int*)(ws + 32768 + 2 * 262144);
        float* psums      = (float*)(ws + 32768 + 2 * 262144 + 32768);

        hipMemsetAsync(cnt, 0, 32768, stream);
        cnorm_kernel<<<K_CODES, 128, 0, stream>>>(cb, cnorm);
        dim3 grid1(N_PTS / FB_MT, FB_SPLIT);
        fb_dist_argmin_kernel<<<grid1, 256, 0, stream>>>(z_e, cb, cnorm, pmin, pidx);
        fb_gather_kernel<<<N_PTS, 128, 0, stream>>>(z_e, cb, pmin, pidx,
                                                    out, out + OUT0_N, cnt, psums);
        finalize_kernel<<<1, 256, 0, stream>>>(cnt, psums, out + OUT0_N + N_PTS);
    }
}

// Round 7
// 341.361 us; speedup vs baseline: 6.5766x; 1.1576x over previous
//
#include <hip/hip_runtime.h>

// ---------------------------------------------------------------------------
// VectorQuantizer: N=16384 points x K=8192 codes x D=512 fp32.
// Fast path (R7): pure-fp16 screening GEMM, K'=512 (dot ~= h_x.h_c; dropped
// cross terms sigma ~9e-4 << 1.5e-2 margin = 17 sigma), fused top-2 argmin
// epilogue (XOR-swizzled LDS, 0 bank conflicts), fused gather with PARALLEL
// split-merge (R6 had a 64-deep serial uniform-load chain) + fp64 rescore of
// near-ties. Prep kernels + counts-zeroing fused into one launch.
// Fallback (small ws): round-1 pure-fp32 VALU kernel (known-correct).
// ---------------------------------------------------------------------------

#define N_PTS   16384
#define DIM     512
#define K_CODES 8192
#define KB      512                   // screening K (hi only)
#define NSPLIT  16                    // code splits (512 codes each)
#define OUT0_N  (N_PTS * DIM)
#define NELEM_F (8388608.0f)
#define MARGIN  1.5e-2f

typedef _Float16 half8 __attribute__((ext_vector_type(8)));
typedef _Float16 f16x4 __attribute__((ext_vector_type(4)));
typedef float    f32x4 __attribute__((ext_vector_type(4)));

// fast-path workspace layout (bytes)
#define SZ_A3    (16384UL * 512 * 2)               // 16.8 MB
#define SZ_B3    (8192UL * 512 * 2)                // 8.4 MB
#define OFF_A3   0UL
#define OFF_B3   (OFF_A3 + SZ_A3)
#define OFF_CN   (OFF_B3 + SZ_B3)                  // cnorm 32 KB
#define OFF_PV1  (OFF_CN + 32768UL)
#define SZ_P     (16UL * 16384 * 4)                // 1 MB each
#define OFF_PI1  (OFF_PV1 + SZ_P)
#define OFF_PV2  (OFF_PI1 + SZ_P)
#define OFF_PI2  (OFF_PV2 + SZ_P)
#define OFF_PSUM (OFF_PI2 + SZ_P)                  // psums 64 KB
#define OFF_CNT  (OFF_PSUM + 65536UL)              // counts 32 KB
#define WS_NEED  (OFF_CNT + 32768UL)

#define GLOAD_LDS16(g, l) \
    __builtin_amdgcn_global_load_lds( \
        (const __attribute__((address_space(1))) unsigned int*)(g), \
        (__attribute__((address_space(3))) unsigned int*)(l), 16, 0, 0)

// ---------------------------------------------------------------- prep (fused)
// blocks [0, N_PTS): cast z_e row -> A3.  blocks [N_PTS, N_PTS+K_CODES):
// cast cb row -> B3 and compute cnorm.  blocks [0,64) also zero the 8192
// histogram counts (stream-ordered before gather).
__global__ __launch_bounds__(128) void prep_all(const float* __restrict__ z_e,
                                                const float* __restrict__ cb,
                                                _Float16* __restrict__ A3,
                                                _Float16* __restrict__ B3,
                                                float* __restrict__ cnorm,
                                                unsigned int* __restrict__ counts) {
    const int b = blockIdx.x;
    const int t = threadIdx.x;
    if (b < 64) counts[b * 128 + t] = 0u;
    if (b < N_PTS) {
        const long r = b;
        const int d = t * 4;
        const float4 v = *(const float4*)(z_e + r * DIM + d);
        f16x4 h;
        h[0] = (_Float16)v.x; h[1] = (_Float16)v.y;
        h[2] = (_Float16)v.z; h[3] = (_Float16)v.w;
        *(f16x4*)(A3 + r * 512 + d) = h;
    } else {
        const long r = b - N_PTS;
        const int d = t * 4;
        const float4 v = *(const float4*)(cb + r * DIM + d);
        f16x4 h;
        h[0] = (_Float16)v.x; h[1] = (_Float16)v.y;
        h[2] = (_Float16)v.z; h[3] = (_Float16)v.w;
        *(f16x4*)(B3 + r * 512 + d) = h;
        float s = v.x * v.x + v.y * v.y + v.z * v.z + v.w * v.w;
#pragma unroll
        for (int o = 32; o > 0; o >>= 1) s += __shfl_down(s, o, 64);
        __shared__ float red[2];
        if ((t & 63) == 0) red[t >> 6] = s;
        __syncthreads();
        if (t == 0) cnorm[r] = red[0] + red[1];
    }
}

// ---------------------------------------------------------------- cnorm (fallback)
__global__ __launch_bounds__(128) void cnorm_kernel(const float* __restrict__ cb,
                                                    float* __restrict__ cnorm) {
    const int k = blockIdx.x;
    const int t = threadIdx.x;
    const float4 v = *(const float4*)(cb + (size_t)k * DIM + t * 4);
    float s = v.x * v.x + v.y * v.y + v.z * v.z + v.w * v.w;
#pragma unroll
    for (int o = 32; o > 0; o >>= 1) s += __shfl_down(s, o, 64);
    __shared__ float red[2];
    if ((t & 63) == 0) red[t >> 6] = s;
    __syncthreads();
    if (t == 0) cnorm[k] = red[0] + red[1];
}

// ---------------------------------------------------------------- score GEMM
// 128x128 tile, BK=64, global_load_lds w=16, 4 waves 2x2, each wave 64x64
// via 4x4 of 16x16x32 f16 MFMA. Block loops 4 code tiles (one 512-code
// split) over K'=512. LDS XOR-swizzled at 16B-chunk granularity (R4:
// conflicts -> 0). Top-2 (val, packed idx) per point-slot; inter-wave LDS
// merge epilogue (R3 race fix).  [UNCHANGED from R6 — verified absmax 0]
__global__ __launch_bounds__(256, 3) void score_kernel(
    const _Float16* __restrict__ A3, const _Float16* __restrict__ B3,
    const float* __restrict__ cnorm,
    float* __restrict__ pv1, int* __restrict__ pi1,
    float* __restrict__ pv2, int* __restrict__ pi2) {
    __shared__ _Float16 As[128 * 64];   // 16 KB
    __shared__ _Float16 Bs[128 * 64];   // 16 KB
    __shared__ float mv1[128][2], mv2[128][2];
    __shared__ int   mj1[128][2], mj2[128][2];

    const int tid = threadIdx.x;
    const int w = tid >> 6;             // wave 0..3
    const int l = tid & 63;
    const int pbase = blockIdx.x * 128;
    const int nsplit = blockIdx.y;      // 0..15
    const int wmb = (w >> 1) * 64;      // wave m offset
    const int wnb = (w & 1) * 64;       // wave n offset
    const int srow = w * 8 + (l >> 3);  // staging row (+ it*32)
    const int scolh = (((l & 7) ^ ((l >> 3) & 7)) * 8);   // swizzled src col

    const _Float16* aB[4];
    const _Float16* bR[4];
#pragma unroll
    for (int it = 0; it < 4; ++it) {
        aB[it] = A3 + (long)(pbase + it * 32 + srow) * 512 + scolh;
        bR[it] = B3 + (long)(it * 32 + srow) * 512 + scolh;
    }

    const int q = l >> 4, x7 = l & 7, m16 = l & 15;
    const int koff0 = ((q ^ x7) * 8);          // ks=0 chunk offset (halves)
    const int rowAf = (wmb + m16) * 64;        // + mi*1024
    const int rowBf = (wnb + m16) * 64;        // + ni*1024

    float v1[16], v2[16];
    int i12[16];                               // (i1<<16) | i2, codes < 8192
#pragma unroll
    for (int s = 0; s < 16; ++s) { v1[s] = 3.0e38f; v2[s] = 3.0e38f; i12[s] = 0; }

#pragma unroll 1
    for (int nt = 0; nt < 4; ++nt) {
        const int kbase = nsplit * 512 + nt * 128;   // code row base
        const long bOff = (long)kbase * 512;
        f32x4 acc[4][4];
#pragma unroll
        for (int mi = 0; mi < 4; ++mi)
#pragma unroll
            for (int ni = 0; ni < 4; ++ni)
                acc[mi][ni] = (f32x4){0.f, 0.f, 0.f, 0.f};

#pragma unroll 1
        for (int kt = 0; kt < KB / 64; ++kt) {       // 8 iterations
            const long ka = (long)kt * 64;
            __syncthreads();                          // LDS reuse guard
#pragma unroll
            for (int it = 0; it < 4; ++it)
                GLOAD_LDS16(aB[it] + ka, &As[it * 2048 + w * 512]);
#pragma unroll
            for (int it = 0; it < 4; ++it)
                GLOAD_LDS16(bR[it] + bOff + ka, &Bs[it * 2048 + w * 512]);
            __syncthreads();                          // drains vmcnt for glds
#pragma unroll
            for (int ks = 0; ks < 2; ++ks) {
                const int ko = koff0 ^ (ks * 32);
                half8 af[4], bf[4];
#pragma unroll
                for (int mi = 0; mi < 4; ++mi)
                    af[mi] = *(half8*)&As[rowAf + mi * 1024 + ko];
#pragma unroll
                for (int ni = 0; ni < 4; ++ni)
                    bf[ni] = *(half8*)&Bs[rowBf + ni * 1024 + ko];
#pragma unroll
                for (int mi = 0; mi < 4; ++mi)
#pragma unroll
                    for (int ni = 0; ni < 4; ++ni)
                        acc[mi][ni] = __builtin_amdgcn_mfma_f32_16x16x32_f16(
                            af[mi], bf[ni], acc[mi][ni], 0, 0, 0);
            }
        }
        // fold this tile's scores into per-lane top2
#pragma unroll
        for (int ni = 0; ni < 4; ++ni) {
            const int k = kbase + wnb + ni * 16 + m16;
            const float cn = cnorm[k];
#pragma unroll
            for (int mi = 0; mi < 4; ++mi)
#pragma unroll
                for (int r = 0; r < 4; ++r) {
                    const float s = fmaf(-2.0f, acc[mi][ni][r], cn);
                    const int slot = mi * 4 + r;
                    if (s < v1[slot]) {               // strict <: lowest k wins
                        v2[slot] = v1[slot];
                        i12[slot] = (k << 16) | (i12[slot] >> 16);
                        v1[slot] = s;
                    } else if (s < v2[slot]) {
                        v2[slot] = s;
                        i12[slot] = (i12[slot] & 0xffff0000) | k;
                    }
                }
        }
    }

    // cross-lane top2 reduce over the 16 lanes sharing each point row,
    // deposit per (point, column-half) into LDS
#pragma unroll
    for (int slot = 0; slot < 16; ++slot) {
        float a1 = v1[slot], a2 = v2[slot];
        int b1 = i12[slot] >> 16, b2 = i12[slot] & 0xffff;
#pragma unroll
        for (int m = 1; m < 16; m <<= 1) {
            const float c1 = __shfl_xor(a1, m, 64);
            const int   d1 = __shfl_xor(b1, m, 64);
            const float c2 = __shfl_xor(a2, m, 64);
            const int   d2 = __shfl_xor(b2, m, 64);
            if (c1 < a1 || (c1 == a1 && d1 < b1)) {
                if (a1 < c2 || (a1 == c2 && b1 < d2)) { a2 = a1; b2 = b1; }
                else { a2 = c2; b2 = d2; }
                a1 = c1; b1 = d1;
            } else {
                if (c1 < a2 || (c1 == a2 && d1 < b2)) { a2 = c1; b2 = d1; }
            }
        }
        if ((l & 15) == 0) {
            const int sm = slot >> 2, sr = slot & 3;
            const int pr = wmb + sm * 16 + (l >> 4) * 4 + sr;  // 0..127
            const int h = w & 1;                               // column half
            mv1[pr][h] = a1; mj1[pr][h] = b1;
            mv2[pr][h] = a2; mj2[pr][h] = b2;
        }
    }
    __syncthreads();
    // merge the two column-halves per point; single global write
    if (tid < 128) {
        float a1 = mv1[tid][0], a2 = mv2[tid][0];
        int b1 = mj1[tid][0], b2 = mj2[tid][0];
        const float c1 = mv1[tid][1], c2 = mv2[tid][1];
        const int   d1 = mj1[tid][1], d2 = mj2[tid][1];
        if (c1 < a1 || (c1 == a1 && d1 < b1)) {
            if (a1 < c2 || (a1 == c2 && b1 < d2)) { a2 = a1; b2 = b1; }
            else { a2 = c2; b2 = d2; }
            a1 = c1; b1 = d1;
        } else {
            if (c1 < a2 || (c1 == a2 && d1 < b2)) { a2 = c1; b2 = d1; }
        }
        const size_t o = (size_t)nsplit * N_PTS + pbase + tid;
        pv1[o] = a1; pi1[o] = b1; pv2[o] = a2; pi2[o] = b2;
    }
}

// ---------------------------------------------------------------- gather
// Fused: PARALLEL merge of split partials (threads 0..15 fetch one split
// each into LDS -> one memory round-trip instead of a 64-deep serial
// uniform-load chain), candidate set + fp64 rescore if any rival within
// MARGIN (block-uniform branch), then gather code row and write z_q_st /
// idx / histogram / partial loss.
__global__ __launch_bounds__(128) void gather_kernel(
    const float* __restrict__ z_e, const float* __restrict__ cb,
    const float* __restrict__ pv1, const int* __restrict__ pi1,
    const float* __restrict__ pv2, const int* __restrict__ pi2,
    float* __restrict__ out_q, float* __restrict__ out_idx,
    unsigned int* __restrict__ counts, float* __restrict__ psums) {
    const int p = blockIdx.x;
    const int t = threadIdx.x;

    __shared__ float sv1[NSPLIT], sv2[NSPLIT];
    __shared__ int   si1[NSPLIT], si2[NSPLIT];
    if (t < NSPLIT) {
        const size_t o = (size_t)t * N_PTS + p;
        sv1[t] = pv1[o]; si1[t] = pi1[o];
        sv2[t] = pv2[o]; si2[t] = pi2[o];
    }
    __syncthreads();

    // merge scan over LDS (broadcast reads; every thread computes the same)
    float bv = 3.0e38f; int bi = 0x7fffffff;
#pragma unroll
    for (int s = 0; s < NSPLIT; ++s) {
        const float v = sv1[s];
        const int i = si1[s];
        if (v < bv || (v == bv && i < bi)) { bv = v; bi = i; }
    }
    float second = 3.0e38f;
    int cand[8]; int nc = 1; cand[0] = bi;
#pragma unroll
    for (int s = 0; s < NSPLIT; ++s) {
        const float v = sv1[s];
        const int i = si1[s];
        const float w2 = sv2[s];
        const int j = si2[s];
        if (i != bi) {
            if (v < second) second = v;
            if (v <= bv + MARGIN && nc < 8) cand[nc++] = i;
        }
        if (j != bi) {
            if (w2 < second) second = w2;
            if (w2 <= bv + MARGIN && nc < 8) cand[nc++] = j;
        }
    }

    __shared__ double dred[2];
    if (second - bv <= MARGIN && nc > 1) {     // block-uniform condition
        double bestv = 1.0e300; int besti = 0x7fffffff;
        for (int c = 0; c < nc; ++c) {
            const int k = cand[c];
            double part = 0.0;
#pragma unroll
            for (int j = 0; j < 4; ++j) {
                const int d = t * 4 + j;
                const double cv = (double)cb[(size_t)k * DIM + d];
                const double zv = (double)z_e[(size_t)p * DIM + d];
                part += cv * cv - 2.0 * zv * cv;
            }
#pragma unroll
            for (int o = 32; o > 0; o >>= 1) part += __shfl_down(part, o, 64);
            if ((t & 63) == 0) dred[t >> 6] = part;
            __syncthreads();
            const double s = dred[0] + dred[1];
            __syncthreads();
            if (s < bestv || (s == bestv && k < besti)) { bestv = s; besti = k; }
        }
        bi = besti;
    }

    const float4 z = *(const float4*)(z_e + (size_t)p * DIM + t * 4);
    const float4 c = *(const float4*)(cb + (size_t)bi * DIM + t * 4);
    float4 d, o;
    d.x = c.x - z.x; d.y = c.y - z.y; d.z = c.z - z.z; d.w = c.w - z.w;
    o.x = z.x + d.x; o.y = z.y + d.y; o.z = z.z + d.z; o.w = z.w + d.w;
    *(float4*)(out_q + (size_t)p * DIM + t * 4) = o;
    float ls = d.x * d.x + d.y * d.y + d.z * d.z + d.w * d.w;
#pragma unroll
    for (int off = 32; off > 0; off >>= 1) ls += __shfl_down(ls, off, 64);
    __shared__ float red[2];
    if ((t & 63) == 0) red[t >> 6] = ls;
    __syncthreads();
    if (t == 0) {
        psums[p] = red[0] + red[1];
        out_idx[p] = (float)bi;
        atomicAdd(&counts[bi], 1u);
    }
}

// ---------------------------------------------------------------- finalize
__global__ __launch_bounds__(256) void finalize_kernel(
    const unsigned int* __restrict__ counts, const float* __restrict__ psums,
    float* __restrict__ out_scalars) {
    const int t = threadIdx.x;
    float ent = 0.0f;
    for (int b = t; b < K_CODES; b += 256) {
        const float pr = (float)counts[b] * (1.0f / 16384.0f);
        ent += pr * logf(pr + 1e-10f);
    }
    float ss = 0.0f;
    for (int i = t; i < N_PTS; i += 256) ss += psums[i];
#pragma unroll
    for (int off = 32; off > 0; off >>= 1) {
        ent += __shfl_down(ent, off, 64);
        ss += __shfl_down(ss, off, 64);
    }
    __shared__ float re[4], rs[4];
    if ((t & 63) == 0) { re[t >> 6] = ent; rs[t >> 6] = ss; }
    __syncthreads();
    if (t == 0) {
        const float loss = (rs[0] + rs[1] + rs[2] + rs[3]) * (1.0f / NELEM_F);
        out_scalars[0] = loss;
        out_scalars[1] = loss;
        out_scalars[2] = expf(-(re[0] + re[1] + re[2] + re[3]));
    }
}

// ================================================================ fallback
// round-1 pure fp32 path (used only if ws_size < WS_NEED)
#define FB_SPLIT 4
#define FB_KS    (K_CODES / FB_SPLIT)
#define FB_MT    128
#define FB_KT    128
#define FB_DT    32
#define FB_PITCH 36

__global__ __launch_bounds__(256, 2) void fb_dist_argmin_kernel(
    const float* __restrict__ z_e, const float* __restrict__ cb,
    const float* __restrict__ cnorm,
    float* __restrict__ pmin, int* __restrict__ pidx) {
    __shared__ float xs[FB_MT * FB_PITCH];
    __shared__ float cs[FB_KT * FB_PITCH];
    const int tid = threadIdx.x;
    const int tx = tid & 15, ty = tid >> 4;
    const int pbase = blockIdx.x * FB_MT;
    const int kbase0 = blockIdx.y * FB_KS;
    const int scol = (tid & 7) * 4, srow0 = tid >> 3;
    float mn[8], acc[8][8];
    int mi[8];
#pragma unroll
    for (int i = 0; i < 8; ++i) { mn[i] = 3.0e38f; mi[i] = 0; }
    for (int kt = 0; kt < FB_KS / FB_KT; ++kt) {
        const int kbase = kbase0 + kt * FB_KT;
#pragma unroll
        for (int i = 0; i < 8; ++i)
#pragma unroll
            for (int j = 0; j < 8; ++j) acc[i][j] = 0.0f;
        for (int dc = 0; dc < DIM / FB_DT; ++dc) {
            const int dbase = dc * FB_DT;
            __syncthreads();
#pragma unroll
            for (int it = 0; it < 4; ++it) {
                const int row = srow0 + it * 32;
                *(float4*)(xs + row * FB_PITCH + scol) =
                    *(const float4*)(z_e + (size_t)(pbase + row) * DIM + dbase + scol);
                *(float4*)(cs + row * FB_PITCH + scol) =
                    *(const float4*)(cb + (size_t)(kbase + row) * DIM + dbase + scol);
            }
            __syncthreads();
#pragma unroll 2
            for (int dd = 0; dd < FB_DT; dd += 4) {
                float4 xv[8], cv[8];
#pragma unroll
                for (int i = 0; i < 8; ++i)
                    xv[i] = *(const float4*)(xs + (ty + 16 * i) * FB_PITCH + dd);
#pragma unroll
                for (int j = 0; j < 8; ++j)
                    cv[j] = *(const float4*)(cs + (tx + 16 * j) * FB_PITCH + dd);
#pragma unroll
                for (int i = 0; i < 8; ++i)
#pragma unroll
                    for (int j = 0; j < 8; ++j)
                        acc[i][j] += xv[i].x * cv[j].x + xv[i].y * cv[j].y +
                                     xv[i].z * cv[j].z + xv[i].w * cv[j].w;
            }
        }
#pragma unroll
        for (int j = 0; j < 8; ++j) {
            const int k = kbase + tx + 16 * j;
            const float cn = cnorm[k];
#pragma unroll
            for (int i = 0; i < 8; ++i) {
                const float s = cn - 2.0f * acc[i][j];
                if (s < mn[i]) { mn[i] = s; mi[i] = k; }
            }
        }
    }
    float* rmin = xs;
    int* ridx = (int*)cs;
    __syncthreads();
#pragma unroll
    for (int i = 0; i < 8; ++i) {
        const int p = ty + 16 * i;
        rmin[p * 16 + tx] = mn[i];
        ridx[p * 16 + tx] = mi[i];
    }
    __syncthreads();
    if (tid < FB_MT) {
        float best = rmin[tid * 16];
        int bi = ridx[tid * 16];
#pragma unroll
        for (int t = 1; t < 16; ++t) {
            const float v = rmin[tid * 16 + t];
            const int k2 = ridx[tid * 16 + t];
            if (v < best || (v == best && k2 < bi)) { best = v; bi = k2; }
        }
        pmin[(size_t)blockIdx.y * N_PTS + pbase + tid] = best;
        pidx[(size_t)blockIdx.y * N_PTS + pbase + tid] = bi;
    }
}

__global__ __launch_bounds__(128) void fb_gather_kernel(
    const float* __restrict__ z_e, const float* __restrict__ cb,
    const float* __restrict__ pmin, const int* __restrict__ pidx,
    float* __restrict__ out_q, float* __restrict__ out_idx,
    unsigned int* __restrict__ counts, float* __restrict__ psums) {
    const int p = blockIdx.x;
    const int t = threadIdx.x;
    float best = pmin[p];
    int bi = pidx[p];
#pragma unroll
    for (int s = 1; s < FB_SPLIT; ++s) {
        const float v = pmin[(size_t)s * N_PTS + p];
        const int k2 = pidx[(size_t)s * N_PTS + p];
        if (v < best || (v == best && k2 < bi)) { best = v; bi = k2; }
    }
    const float4 z = *(const float4*)(z_e + (size_t)p * DIM + t * 4);
    const float4 c = *(const float4*)(cb + (size_t)bi * DIM + t * 4);
    float4 d, o;
    d.x = c.x - z.x; d.y = c.y - z.y; d.z = c.z - z.z; d.w = c.w - z.w;
    o.x = z.x + d.x; o.y = z.y + d.y; o.z = z.z + d.z; o.w = z.w + d.w;
    *(float4*)(out_q + (size_t)p * DIM + t * 4) = o;
    float ls = d.x * d.x + d.y * d.y + d.z * d.z + d.w * d.w;
#pragma unroll
    for (int off = 32; off > 0; off >>= 1) ls += __shfl_down(ls, off, 64);
    __shared__ float red[2];
    if ((t & 63) == 0) red[t >> 6] = ls;
    __syncthreads();
    if (t == 0) {
        psums[p] = red[0] + red[1];
        out_idx[p] = (float)bi;
        atomicAdd(&counts[bi], 1u);
    }
}

// ================================================================ launch
extern "C" void kernel_launch(void* const* d_in, const int* in_sizes, int n_in,
                              void* d_out, int out_size, void* d_ws, size_t ws_size,
                              hipStream_t stream) {
    const float* z_e = (const float*)d_in[0];
    const float* cb  = (const float*)d_in[1];
    float* out = (float*)d_out;
    char* ws = (char*)d_ws;

    if (ws_size >= WS_NEED) {
        _Float16* A3      = (_Float16*)(ws + OFF_A3);
        _Float16* B3      = (_Float16*)(ws + OFF_B3);
        float* cnorm      = (float*)(ws + OFF_CN);
        float* pv1        = (float*)(ws + OFF_PV1);
        int* pi1          = (int*)(ws + OFF_PI1);
        float* pv2        = (float*)(ws + OFF_PV2);
        int* pi2          = (int*)(ws + OFF_PI2);
        float* psums      = (float*)(ws + OFF_PSUM);
        unsigned int* cnt = (unsigned int*)(ws + OFF_CNT);

        prep_all<<<N_PTS + K_CODES, 128, 0, stream>>>(z_e, cb, A3, B3, cnorm, cnt);
        dim3 g(N_PTS / 128, NSPLIT);                   // 128 x 16 blocks
        score_kernel<<<g, 256, 0, stream>>>(A3, B3, cnorm, pv1, pi1, pv2, pi2);
        gather_kernel<<<N_PTS, 128, 0, stream>>>(z_e, cb, pv1, pi1, pv2, pi2,
                                                 out, out + OUT0_N, cnt, psums);
        finalize_kernel<<<1, 256, 0, stream>>>(cnt, psums, out + OUT0_N + N_PTS);
    } else {
        // round-1 fp32 fallback (<700 KB ws)
        float* cnorm      = (float*)ws;
        float* pmin       = (float*)(ws + 32768);
        int* pidx         = (int*)(ws + 32768 + 262144);
        unsigned int* cnt = (unsigned int*)(ws + 32768 + 2 * 262144);
        float* psums      = (float*)(ws + 32768 + 2 * 262144 + 32768);

        hipMemsetAsync(cnt, 0, 32768, stream);
        cnorm_kernel<<<K_CODES, 128, 0, stream>>>(cb, cnorm);
        dim3 grid1(N_PTS / FB_MT, FB_SPLIT);
        fb_dist_argmin_kernel<<<grid1, 256, 0, stream>>>(z_e, cb, cnorm, pmin, pidx);
        fb_gather_kernel<<<N_PTS, 128, 0, stream>>>(z_e, cb, pmin, pidx,
                                                    out, out + OUT0_N, cnt, psums);
        finalize_kernel<<<1, 256, 0, stream>>>(cnt, psums, out + OUT0_N + N_PTS);
    }
}